// Round 2
// baseline (354.414 us; speedup 1.0000x reference)
//
#include <hip/hip_runtime.h>
#include <hip/hip_bf16.h>

// Problem constants. Harness: fp32 inputs, fp32 output buffer.
constexpr int BB = 2;
constexpr int SS = 2048;
constexpr int EMBED = 2048;
constexpr int NH = 32;
constexpr int NKV = 8;
constexpr int HD = 64;
constexpr int WIN = 128;
constexpr int M_ROWS = BB * SS;           // 4096
constexpr int QKVC = 3072;                // packed qkv columns
constexpr float SCALE = 0.125f;

typedef __bf16 bf16x8 __attribute__((ext_vector_type(8)));
typedef float f32x4 __attribute__((ext_vector_type(4)));

__device__ inline uint4 cvt8(float4 lo, float4 hi) {
    union { __hip_bfloat16 h[8]; uint4 u; } r;
    r.h[0] = __hip_bfloat16(lo.x); r.h[1] = __hip_bfloat16(lo.y);
    r.h[2] = __hip_bfloat16(lo.z); r.h[3] = __hip_bfloat16(lo.w);
    r.h[4] = __hip_bfloat16(hi.x); r.h[5] = __hip_bfloat16(hi.y);
    r.h[6] = __hip_bfloat16(hi.z); r.h[7] = __hip_bfloat16(hi.w);
    return r.u;
}
__device__ inline uint4 load8(const float* p) {
    float4 lo = *(const float4*)p;
    float4 hi = *(const float4*)(p + 4);
    return cvt8(lo, hi);
}

// async global->LDS, 16B per lane (wave-uniform base + lane*16).
__device__ inline void gload_lds16(const __hip_bfloat16* g, uint4* l) {
    __builtin_amdgcn_global_load_lds(
        (const __attribute__((address_space(1))) void*)g,
        (__attribute__((address_space(3))) void*)l, 16, 0, 0);
}

// ---------------------------------------------------------------------------
// prep: convert x -> xb and pack wq|wk|wv -> wqkv (bf16). 2048 elems/block.
// ---------------------------------------------------------------------------
__global__ __launch_bounds__(256) void prep_cvt(
    const float* __restrict__ x,  const float* __restrict__ wq,
    const float* __restrict__ wk, const float* __restrict__ wv,
    __hip_bfloat16* __restrict__ xb, __hip_bfloat16* __restrict__ wqkv)
{
    long bid = blockIdx.x;
    const float* src; __hip_bfloat16* dst; long off;
    if (bid < 4096)      { src = x;  dst = xb;             off = bid * 2048; }
    else if (bid < 6144) { src = wq; dst = wqkv;           off = (bid - 4096) * 2048; }
    else if (bid < 6656) { src = wk; dst = wqkv + 4194304; off = (bid - 6144) * 2048; }
    else                 { src = wv; dst = wqkv + 5242880; off = (bid - 6656) * 2048; }
    long i = off + (long)threadIdx.x * 8;
    *(uint4*)(dst + i) = load8(src + i);
}

__global__ __launch_bounds__(256) void cvt_bf16(
    const float* __restrict__ in, __hip_bfloat16* __restrict__ out, long n)
{
    long i = ((long)blockIdx.x * 256 + threadIdx.x) * 8;
    if (i + 8 <= n) *(uint4*)(out + i) = load8(in + i);
}

// ---------------------------------------------------------------------------
// BMxBN 8-phase GEMM (T3+T4+T5). C[M][N] = A[M][K]·B[N][K]^T, bf16 in, TC out.
// 512 threads = 8 waves (2M x 4N). BK=64 split into two ks-sub-buffers.
//
// LDS layout (T2, conflict-free without XOR): each ks-sub-buffer is
// chunk-major [4 k-slots][ROWS] of 16B chunks (chunk = q*ROWS + row holds
// row's k-elems q*8..q*8+7). Frag read (row, quad) -> chunk quad*ROWS+row
// -> bank_start (lrow&7)*4: 8 starts x 2 lanes = the m97-verified clean
// pattern (quad stride 4096B == 0 mod 128). Staging keeps the REQUIRED
// linear global_load_lds dest; the layout permutation is applied to the
// per-thread global SOURCE instead (thread t sources row t%ROWS, slot
// t/ROWS) -- both-sides-consistent per rule #21.
//
// Counted vmcnt (T4): VMN = loads per tile-half; waiting to VMN at phases
// 1 and 3 retires exactly the sub-buffers the next phase-pair reads while
// keeping the current tile-half's loads in flight (never drains to 0).
// K % 128 == 0 required (2 K-tiles per iter so buffer index is literal).
// ---------------------------------------------------------------------------
#define BAR() __builtin_amdgcn_s_barrier()
#define LGKM0() do { \
    asm volatile("s_waitcnt lgkmcnt(0)" ::: "memory"); \
    __builtin_amdgcn_sched_barrier(0); } while (0)
#define VMCN() do { \
    if constexpr (VMN == 4) asm volatile("s_waitcnt vmcnt(4)" ::: "memory"); \
    else                    asm volatile("s_waitcnt vmcnt(3)" ::: "memory"); } while (0)

#define STAGE_A(NB, KS, KOFF) do { \
    __hip_bfloat16* _d = &lds[(NB) * DB + (KS) * ASZ + t * 8]; \
    gload_lds16(pA + (KOFF) + (KS) * 32, (uint4*)_d); \
    if constexpr (ALD == 2) \
        gload_lds16(pA + (KOFF) + (KS) * 32 + 16, (uint4*)(_d + 4096)); \
} while (0)

#define STAGE_B(NB, KS, KOFF) do { \
    __hip_bfloat16* _d = &lds[(NB) * DB + 2 * ASZ + (KS) * BSZ + t * 8]; \
    gload_lds16(pB + (KOFF) + (KS) * 32, (uint4*)_d); \
    gload_lds16(pB + (KOFF) + (KS) * 32 + 16, (uint4*)(_d + 4096)); \
} while (0)

#define LOAD_A(CB, MI0, KS) \
    _Pragma("unroll") for (int _i = 0; _i < MIH; ++_i) \
        af[_i] = *(const bf16x8*)&lds[(CB) + (KS) * ASZ + aoff + ((MI0) + _i) * 128];

#define LOAD_B(CB, KS) \
    _Pragma("unroll") for (int _n = 0; _n < 4; ++_n) \
        bfr[_n] = *(const bf16x8*)&lds[(CB) + 2 * ASZ + (KS) * BSZ + boff + _n * 128];

#define MFMA_HALF(MI0) \
    _Pragma("unroll") for (int _i = 0; _i < MIH; ++_i) { \
        _Pragma("unroll") for (int _n = 0; _n < 4; ++_n) \
            acc[(MI0) + _i][_n] = __builtin_amdgcn_mfma_f32_16x16x32_bf16( \
                af[_i], bfr[_n], acc[(MI0) + _i][_n], 0, 0, 0); \
    }

#define KTILE(CUR, KT) do { \
    const long kn = (long)(((KT) + 1 < nkt) ? ((KT) + 1) : (KT)) << 6; \
    constexpr int cb = (CUR) * DB; \
    constexpr int nb = (CUR) ^ 1; \
    /* phase 0: ks0, mi 0..MIH */ \
    LOAD_B(cb, 0); LOAD_A(cb, 0, 0); \
    STAGE_A(nb, 0, kn); \
    BAR(); LGKM0(); \
    __builtin_amdgcn_s_setprio(1); MFMA_HALF(0); __builtin_amdgcn_s_setprio(0); \
    BAR(); \
    /* phase 1: ks0, mi MIH.. */ \
    LOAD_A(cb, MIH, 0); \
    STAGE_B(nb, 0, kn); \
    BAR(); LGKM0(); \
    __builtin_amdgcn_s_setprio(1); MFMA_HALF(MIH); __builtin_amdgcn_s_setprio(0); \
    VMCN(); BAR(); \
    /* phase 2: ks1, mi 0..MIH */ \
    LOAD_B(cb, 1); LOAD_A(cb, 0, 1); \
    STAGE_A(nb, 1, kn); \
    BAR(); LGKM0(); \
    __builtin_amdgcn_s_setprio(1); MFMA_HALF(0); __builtin_amdgcn_s_setprio(0); \
    BAR(); \
    /* phase 3: ks1, mi MIH.. */ \
    LOAD_A(cb, MIH, 1); \
    STAGE_B(nb, 1, kn); \
    BAR(); LGKM0(); \
    __builtin_amdgcn_s_setprio(1); MFMA_HALF(MIH); __builtin_amdgcn_s_setprio(0); \
    VMCN(); BAR(); \
} while (0)

template <typename TC, int BM, int BN>
__global__ __launch_bounds__(512) void gemm256(
    const __hip_bfloat16* __restrict__ A,
    const __hip_bfloat16* __restrict__ Bm,
    TC* __restrict__ C, int K, int ldc, int nbx)
{
    constexpr int MI  = BM / 32;          // mfma row-frags per wave
    constexpr int MIH = MI / 2;
    constexpr int ASZ = BM * 32;          // elems per A ks-sub-buffer
    constexpr int BSZ = BN * 32;
    constexpr int DB  = 2 * (ASZ + BSZ);  // elems per double-buffer
    constexpr int ALD = BM / 128;         // gloads per A ks-sub
    constexpr int VMN = ALD + BN / 128;   // counted vmcnt value

    __shared__ __hip_bfloat16 lds[2 * DB];

    const int t = threadIdx.x;
    const int lane = t & 63;
    const int wid = t >> 6;
    const int wm = wid >> 2;                // 0..1
    const int wn = wid & 3;                 // 0..3
    const int lrow = lane & 15;
    const int quad = lane >> 4;

    // bijective XCD swizzle (nwg % 8 == 0 for both call sites)
    int bid = blockIdx.x;
    const int nwg = gridDim.x;
    if ((nwg & 7) == 0) bid = (bid & 7) * (nwg >> 3) + (bid >> 3);
    const long blockM = (long)(bid / nbx) * BM;
    const long blockN = (long)(bid % nbx) * BN;

    // staging sources: thread t fills chunk t (+512) of a ks-sub = row t%ROWS,
    // k-slot t/ROWS (source permuted, dest linear).
    const __hip_bfloat16* pA = A  + (blockM + (t % BM)) * (long)K + (t / BM) * 8;
    const __hip_bfloat16* pB = Bm + (blockN + (t % BN)) * (long)K + (t / BN) * 8;

    // frag read offsets (elems): chunk = quad*ROWS + row
    const int aoff = (quad * BM + wm * (BM / 2) + lrow) * 8;
    const int boff = (quad * BN + wn * 64 + lrow) * 8;

    // prologue: stage all 4 sub-buffers of tile 0 into buf 0, drain once
    STAGE_A(0, 0, 0); STAGE_B(0, 0, 0);
    STAGE_A(0, 1, 0); STAGE_B(0, 1, 0);
    asm volatile("s_waitcnt vmcnt(0)" ::: "memory");
    BAR();

    f32x4 acc[MI][4] = {};
    bf16x8 af[MIH], bfr[4];
    const int nkt = K >> 6;

    for (int kt = 0; kt < nkt; kt += 2) {
        KTILE(0, kt);
        KTILE(1, kt + 1);
    }

    asm volatile("s_waitcnt vmcnt(0)" ::: "memory");

    #pragma unroll
    for (int mi = 0; mi < MI; ++mi)
        #pragma unroll
        for (int ni = 0; ni < 4; ++ni)
            #pragma unroll
            for (int r = 0; r < 4; ++r) {
                long rr = blockM + wm * (BM / 2) + mi * 16 + quad * 4 + r;
                long cc = blockN + wn * 64 + ni * 16 + lrow;
                C[rr * (long)ldc + cc] = TC(acc[mi][ni][r]);
            }
}

// ---------------------------------------------------------------------------
// Per-head RMSNorm + RoPE, in place on packed qkv[row][3072].
// ---------------------------------------------------------------------------
__global__ __launch_bounds__(256) void norm_rope(
    __hip_bfloat16* __restrict__ qkv,
    const float* __restrict__ qw,
    const float* __restrict__ kw)
{
    const int QROWS = M_ROWS * NH;      // 131072
    int gid = blockIdx.x * 4 + (threadIdx.x >> 6);
    int lane = threadIdx.x & 63;

    __hip_bfloat16* base;
    const float* wptr;
    int s;
    if (gid < QROWS) {
        int row = gid >> 5;             // /NH
        base = qkv + (long)row * QKVC + (gid & 31) * HD;
        s = row % SS;
        wptr = qw;
    } else {
        int g = gid - QROWS;
        int row = g >> 3;               // /NKV
        base = qkv + (long)row * QKVC + 2048 + (g & 7) * HD;
        s = row % SS;
        wptr = kw;
    }

    float x = (float)base[lane];
    float ss = x * x;
    for (int off = 32; off; off >>= 1) ss += __shfl_xor(ss, off);
    float scale = rsqrtf(ss * (1.0f / 64.0f) + 1e-6f);
    float xn = x * scale * wptr[lane];

    float partner = __shfl_xor(xn, 32);
    int i = lane & 31;
    float ang = (float)s * powf(10000.0f, -(float)i * (1.0f / 32.0f));
    float sn, cs;
    sincosf(ang, &sn, &cs);
    float y = (lane < 32) ? (xn * cs - partner * sn) : (xn * cs + partner * sn);
    base[lane] = __hip_bfloat16(y);
}

// ---------------------------------------------------------------------------
// MFMA sliding-window attention with sink, reading packed qkv[row][3072].
// ---------------------------------------------------------------------------
constexpr int SPAN = 192;
constexpr int KROW = 72;
constexpr int PROW = 200;

__global__ __launch_bounds__(256) void attn_mfma(
    const __hip_bfloat16* __restrict__ qkv,
    const int* __restrict__ amask,
    const float* __restrict__ sinks,
    __hip_bfloat16* __restrict__ ao)     // [4096][2048] (b,s,h,d)
{
    __shared__ __hip_bfloat16 KsPs[SPAN * KROW];
    __shared__ __hip_bfloat16 Vt[64 * PROW];

    const int bid = blockIdx.x;
    const int qt = bid & 31;
    const int h = (bid >> 5) & 31;
    const int b = bid >> 10;
    const int kv = h >> 2;
    const int q0 = qt * 64;
    const int base = q0 - (WIN - 1);
    const int t = threadIdx.x;
    const int w = t >> 6;
    const int lane = t & 63;
    const int lrow = lane & 15;
    const int quad = lane >> 4;

    for (int c = t; c < SPAN * 8; c += 256) {
        int j = c >> 3;
        int d0 = (c & 7) * 8;
        int kg = base + j;
        uint4 kk = {0, 0, 0, 0}, vv = {0, 0, 0, 0};
        if (kg >= 0 && kg < SS) {
            long rowoff = ((long)b * SS + kg) * QKVC + kv * HD + d0;
            kk = *(const uint4*)(qkv + rowoff + 2048);
            vv = *(const uint4*)(qkv + rowoff + 2560);
        }
        *(uint4*)&KsPs[j * KROW + d0] = kk;
        const __hip_bfloat16* vp = (const __hip_bfloat16*)&vv;
        #pragma unroll
        for (int u = 0; u < 8; u++) Vt[(d0 + u) * PROW + j] = vp[u];
    }
    __syncthreads();

    const __hip_bfloat16* qrow =
        qkv + ((long)b * SS + q0 + w * 16 + lrow) * QKVC + h * HD;
    bf16x8 qa0 = *(const bf16x8*)(qrow + quad * 8);
    bf16x8 qa1 = *(const bf16x8*)(qrow + 32 + quad * 8);

    f32x4 s[12] = {};
    #pragma unroll
    for (int ni = 0; ni < 12; ni++) {
        bf16x8 kb0 = *(const bf16x8*)&KsPs[(ni * 16 + lrow) * KROW + quad * 8];
        bf16x8 kb1 = *(const bf16x8*)&KsPs[(ni * 16 + lrow) * KROW + 32 + quad * 8];
        s[ni] = __builtin_amdgcn_mfma_f32_16x16x32_bf16(qa0, kb0, s[ni], 0, 0, 0);
        s[ni] = __builtin_amdgcn_mfma_f32_16x16x32_bf16(qa1, kb1, s[ni], 0, 0, 0);
    }

    bool jok[12];
    #pragma unroll
    for (int ni = 0; ni < 12; ni++) {
        int kg = base + ni * 16 + lrow;
        jok[ni] = (kg >= 0) && (kg < SS) && (amask[b * SS + (kg >= 0 && kg < SS ? kg : 0)] > 0);
    }

    const float sinkv = sinks[h];

    #pragma unroll
    for (int reg = 0; reg < 4; reg++) {
        int row = w * 16 + quad * 4 + reg;
        float mrow = -3.0e30f;
        #pragma unroll
        for (int ni = 0; ni < 12; ni++) {
            int j = ni * 16 + lrow;
            bool valid = jok[ni] && (j >= row) && (j <= row + 127);
            float val = valid ? s[ni][reg] * SCALE : -1.0e30f;
            s[ni][reg] = val;
            mrow = fmaxf(mrow, val);
        }
        #pragma unroll
        for (int off = 1; off < 16; off <<= 1) mrow = fmaxf(mrow, __shfl_xor(mrow, off));
        mrow = fmaxf(mrow, sinkv);
        float sum = 0.f;
        #pragma unroll
        for (int ni = 0; ni < 12; ni++) {
            float e = __expf(s[ni][reg] - mrow);
            s[ni][reg] = e;
            sum += e;
        }
        #pragma unroll
        for (int off = 1; off < 16; off <<= 1) sum += __shfl_xor(sum, off);
        sum += __expf(sinkv - mrow);
        float inv = 1.0f / sum;
        #pragma unroll
        for (int ni = 0; ni < 12; ni++) s[ni][reg] *= inv;
    }

    __syncthreads();

    #pragma unroll
    for (int ni = 0; ni < 12; ni++)
        #pragma unroll
        for (int reg = 0; reg < 4; reg++)
            KsPs[(w * 16 + quad * 4 + reg) * PROW + ni * 16 + lrow] =
                __hip_bfloat16(s[ni][reg]);
    __syncthreads();

    f32x4 o[4] = {};
    #pragma unroll
    for (int ks = 0; ks < 6; ks++) {
        bf16x8 pa = *(const bf16x8*)&KsPs[(w * 16 + lrow) * PROW + ks * 32 + quad * 8];
        #pragma unroll
        for (int ni = 0; ni < 4; ni++) {
            bf16x8 vb = *(const bf16x8*)&Vt[(ni * 16 + lrow) * PROW + ks * 32 + quad * 8];
            o[ni] = __builtin_amdgcn_mfma_f32_16x16x32_bf16(pa, vb, o[ni], 0, 0, 0);
        }
    }

    #pragma unroll
    for (int ni = 0; ni < 4; ni++)
        #pragma unroll
        for (int reg = 0; reg < 4; reg++) {
            int row = w * 16 + quad * 4 + reg;
            ao[((long)b * SS + q0 + row) * (NH * HD) + h * HD + ni * 16 + lrow] =
                __hip_bfloat16(o[ni][reg]);
        }
}

// ---------------------------------------------------------------------------
// Scratch plan (harness restores d_in before every launch):
//   d_out (33.5MB): xb[0:16.8M) wqkv[16.8:29.4M)   -- dead before final GEMM
//   x region (33.5MB): qkv[0:25.2M) wob[25.2:33.5M) -- x dead after prep
//   wq region (16.8MB): abuf (attn output)          -- wq dead after prep
// Order: prep -> wo-cvt -> qkv-gemm -> norm -> attn -> final gemm.
// ---------------------------------------------------------------------------
extern "C" void kernel_launch(void* const* d_in, const int* in_sizes, int n_in,
                              void* d_out, int out_size, void* d_ws, size_t ws_size,
                              hipStream_t stream) {
    const float* x     = (const float*)d_in[0];
    const int*   am    = (const int*)d_in[1];
    const float* wq    = (const float*)d_in[2];
    const float* wk    = (const float*)d_in[3];
    const float* wv    = (const float*)d_in[4];
    const float* wo    = (const float*)d_in[5];
    const float* qnw   = (const float*)d_in[6];
    const float* knw   = (const float*)d_in[7];
    const float* sinks = (const float*)d_in[8];
    float* out = (float*)d_out;

    __hip_bfloat16* xb    = (__hip_bfloat16*)d_out;
    __hip_bfloat16* wqkv  = (__hip_bfloat16*)((char*)d_out + 16777216);
    __hip_bfloat16* qkv   = (__hip_bfloat16*)x;
    __hip_bfloat16* wob   = (__hip_bfloat16*)((char*)x + 25165824);
    __hip_bfloat16* abuf  = (__hip_bfloat16*)wq;

    const long NW = (long)EMBED * EMBED;   // 4194304

    // 1. convert x + pack wq|wk|wv (7168 blocks)
    prep_cvt<<<7168, 256, 0, stream>>>(x, wq, wk, wv, xb, wqkv);
    // 2. convert wo into dead x tail
    cvt_bf16<<<NW / 2048, 256, 0, stream>>>(wo, wob, NW);

    // 3. fused QKV projection: qkv[4096][3072], 16x12 = 192 blocks
    gemm256<__hip_bfloat16, 256, 256><<<192, 512, 0, stream>>>(
        xb, wqkv, qkv, EMBED, QKVC, QKVC / 256);

    // 4. RMSNorm + RoPE on q,k inside packed qkv
    int rows = M_ROWS * NH + M_ROWS * NKV;   // 163840
    norm_rope<<<rows / 4, 256, 0, stream>>>(qkv, qnw, knw);

    // 5. attention -> abuf [4096][2048]
    attn_mfma<<<BB * NH * (SS / 64), 256, 0, stream>>>(qkv, am, sinks, abuf);

    // 6. output projection: fp32 into d_out, BM=128/BN=256, 32x8 = 256 blocks
    gemm256<float, 128, 256><<<256, 512, 0, stream>>>(
        abuf, wob, out, EMBED, EMBED, EMBED / 256);
}

// Round 3
// 293.226 us; speedup vs baseline: 1.2087x; 1.2087x over previous
//
#include <hip/hip_runtime.h>
#include <hip/hip_bf16.h>

// Problem constants. Harness: fp32 inputs, fp32 output buffer.
constexpr int BB = 2;
constexpr int SS = 2048;
constexpr int EMBED = 2048;
constexpr int NH = 32;
constexpr int NKV = 8;
constexpr int HD = 64;
constexpr int WIN = 128;
constexpr int M_ROWS = BB * SS;           // 4096
constexpr int QKVC = 3072;                // packed qkv columns
constexpr float SCALE = 0.125f;

typedef __bf16 bf16x8 __attribute__((ext_vector_type(8)));
typedef float f32x4 __attribute__((ext_vector_type(4)));

__device__ inline uint4 cvt8(float4 lo, float4 hi) {
    union { __hip_bfloat16 h[8]; uint4 u; } r;
    r.h[0] = __hip_bfloat16(lo.x); r.h[1] = __hip_bfloat16(lo.y);
    r.h[2] = __hip_bfloat16(lo.z); r.h[3] = __hip_bfloat16(lo.w);
    r.h[4] = __hip_bfloat16(hi.x); r.h[5] = __hip_bfloat16(hi.y);
    r.h[6] = __hip_bfloat16(hi.z); r.h[7] = __hip_bfloat16(hi.w);
    return r.u;
}
__device__ inline uint4 load8(const float* p) {
    float4 lo = *(const float4*)p;
    float4 hi = *(const float4*)(p + 4);
    return cvt8(lo, hi);
}

// async global->LDS, 16B per lane (wave-uniform base + lane*16).
__device__ inline void gload_lds16(const __hip_bfloat16* g, uint4* l) {
    __builtin_amdgcn_global_load_lds(
        (const __attribute__((address_space(1))) void*)g,
        (__attribute__((address_space(3))) void*)l, 16, 0, 0);
}

// ---------------------------------------------------------------------------
// prep: convert x -> xb and pack wq|wk|wv -> wqkv (bf16). 2048 elems/block.
// ---------------------------------------------------------------------------
__global__ __launch_bounds__(256) void prep_cvt(
    const float* __restrict__ x,  const float* __restrict__ wq,
    const float* __restrict__ wk, const float* __restrict__ wv,
    __hip_bfloat16* __restrict__ xb, __hip_bfloat16* __restrict__ wqkv)
{
    long bid = blockIdx.x;
    const float* src; __hip_bfloat16* dst; long off;
    if (bid < 4096)      { src = x;  dst = xb;             off = bid * 2048; }
    else if (bid < 6144) { src = wq; dst = wqkv;           off = (bid - 4096) * 2048; }
    else if (bid < 6656) { src = wk; dst = wqkv + 4194304; off = (bid - 6144) * 2048; }
    else                 { src = wv; dst = wqkv + 5242880; off = (bid - 6656) * 2048; }
    long i = off + (long)threadIdx.x * 8;
    *(uint4*)(dst + i) = load8(src + i);
}

__global__ __launch_bounds__(256) void cvt_bf16(
    const float* __restrict__ in, __hip_bfloat16* __restrict__ out, long n)
{
    long i = ((long)blockIdx.x * 256 + threadIdx.x) * 8;
    if (i + 8 <= n) *(uint4*)(out + i) = load8(in + i);
}

// ---------------------------------------------------------------------------
// BMxBN 8-phase GEMM (T3+T4+T5). C[M][N] = A[M][K]·B[N][K]^T, bf16 in, TC out.
// 512 threads = 8 waves (2M x 4N). BK=64 split into two ks-sub-buffers.
//
// LDS layout (T2 via in-row chunk XOR; rule #21 both-sides):
//   Sub-buffer = [ROWS][4 chunks of 16B], row-major. Physical chunk
//   (row, s_stored) holds logical k-slot s_log = s_stored ^ ((row>>1)&3).
//   - Staging: dest linear (thread t -> chunk t), source permuted WITHIN
//     the row's 64B: thread t reads row t>>2, slot (t&3)^((t>>3)&3) ->
//     4 lanes cover one contiguous 64B row segment (coalesced, = round-1).
//   - Read (row, quad): slot quad^((lrow>>1)&3); bank_start =
//     (lrow&1)*16 + ((quad^((lrow>>1)&3))&3)*4 -> per quarter-wave all 8
//     bank-groups x 2 lanes = conflict-free (m97-verified spread).
//   XOR term is mi/wm/wn-independent (row offsets all == 0 mod 8).
//
// Counted vmcnt (T4): VMN = loads per tile-half (ALD + 2); waiting to VMN
// at phases 1 and 3 retires exactly the sub-buffers the next phase-pair
// reads while keeping the current tile-half's loads in flight (never 0).
// K % 128 == 0 required (2 K-tiles per iter so buffer index is literal).
// ---------------------------------------------------------------------------
#define BAR() __builtin_amdgcn_s_barrier()
#define LGKM0() do { \
    asm volatile("s_waitcnt lgkmcnt(0)" ::: "memory"); \
    __builtin_amdgcn_sched_barrier(0); } while (0)
#define VMCN() do { \
    if constexpr (VMN == 4) asm volatile("s_waitcnt vmcnt(4)" ::: "memory"); \
    else                    asm volatile("s_waitcnt vmcnt(3)" ::: "memory"); } while (0)

#define STAGE_A(NB, KS, KOFF) do { \
    __hip_bfloat16* _d = &lds[(NB) * DB + (KS) * ASZ + t * 8]; \
    gload_lds16(pA + (KOFF) + (KS) * 32, (uint4*)_d); \
    if constexpr (ALD == 2) \
        gload_lds16(pA + 128 * (long)K + (KOFF) + (KS) * 32, (uint4*)(_d + 4096)); \
} while (0)

#define STAGE_B(NB, KS, KOFF) do { \
    __hip_bfloat16* _d = &lds[(NB) * DB + 2 * ASZ + (KS) * BSZ + t * 8]; \
    gload_lds16(pB + (KOFF) + (KS) * 32, (uint4*)_d); \
    gload_lds16(pB + 128 * (long)K + (KOFF) + (KS) * 32, (uint4*)(_d + 4096)); \
} while (0)

#define LOAD_A(CB, MI0, KS) \
    _Pragma("unroll") for (int _i = 0; _i < MIH; ++_i) \
        af[_i] = *(const bf16x8*)&lds[(CB) + (KS) * ASZ + aoff + ((MI0) + _i) * 512];

#define LOAD_B(CB, KS) \
    _Pragma("unroll") for (int _n = 0; _n < 4; ++_n) \
        bfr[_n] = *(const bf16x8*)&lds[(CB) + 2 * ASZ + (KS) * BSZ + boff + _n * 512];

#define MFMA_HALF(MI0) \
    _Pragma("unroll") for (int _i = 0; _i < MIH; ++_i) { \
        _Pragma("unroll") for (int _n = 0; _n < 4; ++_n) \
            acc[(MI0) + _i][_n] = __builtin_amdgcn_mfma_f32_16x16x32_bf16( \
                af[_i], bfr[_n], acc[(MI0) + _i][_n], 0, 0, 0); \
    }

#define KTILE(CUR, KT) do { \
    const long kn = (long)(((KT) + 1 < nkt) ? ((KT) + 1) : (KT)) << 6; \
    constexpr int cb = (CUR) * DB; \
    constexpr int nb = (CUR) ^ 1; \
    /* phase 0: ks0, mi 0..MIH */ \
    LOAD_B(cb, 0); LOAD_A(cb, 0, 0); \
    STAGE_A(nb, 0, kn); \
    BAR(); LGKM0(); \
    __builtin_amdgcn_s_setprio(1); MFMA_HALF(0); __builtin_amdgcn_s_setprio(0); \
    BAR(); \
    /* phase 1: ks0, mi MIH.. */ \
    LOAD_A(cb, MIH, 0); \
    STAGE_B(nb, 0, kn); \
    BAR(); LGKM0(); \
    __builtin_amdgcn_s_setprio(1); MFMA_HALF(MIH); __builtin_amdgcn_s_setprio(0); \
    VMCN(); BAR(); \
    /* phase 2: ks1, mi 0..MIH */ \
    LOAD_B(cb, 1); LOAD_A(cb, 0, 1); \
    STAGE_A(nb, 1, kn); \
    BAR(); LGKM0(); \
    __builtin_amdgcn_s_setprio(1); MFMA_HALF(0); __builtin_amdgcn_s_setprio(0); \
    BAR(); \
    /* phase 3: ks1, mi MIH.. */ \
    LOAD_A(cb, MIH, 1); \
    STAGE_B(nb, 1, kn); \
    BAR(); LGKM0(); \
    __builtin_amdgcn_s_setprio(1); MFMA_HALF(MIH); __builtin_amdgcn_s_setprio(0); \
    VMCN(); BAR(); \
} while (0)

template <typename TC, int BM, int BN>
__global__ __launch_bounds__(512) void gemm256(
    const __hip_bfloat16* __restrict__ A,
    const __hip_bfloat16* __restrict__ Bm,
    TC* __restrict__ C, int K, int ldc, int nbx)
{
    constexpr int MI  = BM / 32;          // mfma row-frags per wave
    constexpr int MIH = MI / 2;
    constexpr int ASZ = BM * 32;          // elems per A ks-sub-buffer
    constexpr int BSZ = BN * 32;
    constexpr int DB  = 2 * (ASZ + BSZ);  // elems per double-buffer
    constexpr int ALD = BM / 128;         // gloads per A ks-sub
    constexpr int VMN = ALD + BN / 128;   // counted vmcnt value

    __shared__ __hip_bfloat16 lds[2 * DB];

    const int t = threadIdx.x;
    const int lane = t & 63;
    const int wid = t >> 6;
    const int wm = wid >> 2;                // 0..1
    const int wn = wid & 3;                 // 0..3
    const int lrow = lane & 15;
    const int quad = lane >> 4;

    // bijective XCD swizzle (nwg % 8 == 0 for both call sites)
    int bid = blockIdx.x;
    const int nwg = gridDim.x;
    if ((nwg & 7) == 0) bid = (bid & 7) * (nwg >> 3) + (bid >> 3);
    const long blockM = (long)(bid / nbx) * BM;
    const long blockN = (long)(bid % nbx) * BN;

    // staging sources: thread t fills physical chunk t of a ks-sub-buffer;
    // row t>>2, logical slot (t&3)^((t>>3)&3) -> contiguous 64B per 4 lanes.
    const int srow = t >> 2;
    const int sslot = ((t & 3) ^ ((t >> 3) & 3)) * 8;
    const __hip_bfloat16* pA = A  + (blockM + srow) * (long)K + sslot;
    const __hip_bfloat16* pB = Bm + (blockN + srow) * (long)K + sslot;

    // frag read offsets (elems): row-major rows of 32 elems, slot XOR'd
    const int xslot = (quad ^ ((lrow >> 1) & 3)) * 8;
    const int aoff = (wm * (BM / 2) + lrow) * 32 + xslot;
    const int boff = (wn * 64 + lrow) * 32 + xslot;

    // prologue: stage all 4 sub-buffers of tile 0 into buf 0, drain once
    STAGE_A(0, 0, 0); STAGE_B(0, 0, 0);
    STAGE_A(0, 1, 0); STAGE_B(0, 1, 0);
    asm volatile("s_waitcnt vmcnt(0)" ::: "memory");
    BAR();

    f32x4 acc[MI][4] = {};
    bf16x8 af[MIH], bfr[4];
    const int nkt = K >> 6;

    for (int kt = 0; kt < nkt; kt += 2) {
        KTILE(0, kt);
        KTILE(1, kt + 1);
    }

    asm volatile("s_waitcnt vmcnt(0)" ::: "memory");

    #pragma unroll
    for (int mi = 0; mi < MI; ++mi)
        #pragma unroll
        for (int ni = 0; ni < 4; ++ni)
            #pragma unroll
            for (int r = 0; r < 4; ++r) {
                long rr = blockM + wm * (BM / 2) + mi * 16 + quad * 4 + r;
                long cc = blockN + wn * 64 + ni * 16 + lrow;
                C[rr * (long)ldc + cc] = TC(acc[mi][ni][r]);
            }
}

// ---------------------------------------------------------------------------
// Per-head RMSNorm + RoPE, in place on packed qkv[row][3072].
// ---------------------------------------------------------------------------
__global__ __launch_bounds__(256) void norm_rope(
    __hip_bfloat16* __restrict__ qkv,
    const float* __restrict__ qw,
    const float* __restrict__ kw)
{
    const int QROWS = M_ROWS * NH;      // 131072
    int gid = blockIdx.x * 4 + (threadIdx.x >> 6);
    int lane = threadIdx.x & 63;

    __hip_bfloat16* base;
    const float* wptr;
    int s;
    if (gid < QROWS) {
        int row = gid >> 5;             // /NH
        base = qkv + (long)row * QKVC + (gid & 31) * HD;
        s = row % SS;
        wptr = qw;
    } else {
        int g = gid - QROWS;
        int row = g >> 3;               // /NKV
        base = qkv + (long)row * QKVC + 2048 + (g & 7) * HD;
        s = row % SS;
        wptr = kw;
    }

    float x = (float)base[lane];
    float ss = x * x;
    for (int off = 32; off; off >>= 1) ss += __shfl_xor(ss, off);
    float scale = rsqrtf(ss * (1.0f / 64.0f) + 1e-6f);
    float xn = x * scale * wptr[lane];

    float partner = __shfl_xor(xn, 32);
    int i = lane & 31;
    float ang = (float)s * powf(10000.0f, -(float)i * (1.0f / 32.0f));
    float sn, cs;
    sincosf(ang, &sn, &cs);
    float y = (lane < 32) ? (xn * cs - partner * sn) : (xn * cs + partner * sn);
    base[lane] = __hip_bfloat16(y);
}

// ---------------------------------------------------------------------------
// MFMA sliding-window attention with sink, reading packed qkv[row][3072].
// ---------------------------------------------------------------------------
constexpr int SPAN = 192;
constexpr int KROW = 72;
constexpr int PROW = 200;

__global__ __launch_bounds__(256) void attn_mfma(
    const __hip_bfloat16* __restrict__ qkv,
    const int* __restrict__ amask,
    const float* __restrict__ sinks,
    __hip_bfloat16* __restrict__ ao)     // [4096][2048] (b,s,h,d)
{
    __shared__ __hip_bfloat16 KsPs[SPAN * KROW];
    __shared__ __hip_bfloat16 Vt[64 * PROW];

    const int bid = blockIdx.x;
    const int qt = bid & 31;
    const int h = (bid >> 5) & 31;
    const int b = bid >> 10;
    const int kv = h >> 2;
    const int q0 = qt * 64;
    const int base = q0 - (WIN - 1);
    const int t = threadIdx.x;
    const int w = t >> 6;
    const int lane = t & 63;
    const int lrow = lane & 15;
    const int quad = lane >> 4;

    for (int c = t; c < SPAN * 8; c += 256) {
        int j = c >> 3;
        int d0 = (c & 7) * 8;
        int kg = base + j;
        uint4 kk = {0, 0, 0, 0}, vv = {0, 0, 0, 0};
        if (kg >= 0 && kg < SS) {
            long rowoff = ((long)b * SS + kg) * QKVC + kv * HD + d0;
            kk = *(const uint4*)(qkv + rowoff + 2048);
            vv = *(const uint4*)(qkv + rowoff + 2560);
        }
        *(uint4*)&KsPs[j * KROW + d0] = kk;
        const __hip_bfloat16* vp = (const __hip_bfloat16*)&vv;
        #pragma unroll
        for (int u = 0; u < 8; u++) Vt[(d0 + u) * PROW + j] = vp[u];
    }
    __syncthreads();

    const __hip_bfloat16* qrow =
        qkv + ((long)b * SS + q0 + w * 16 + lrow) * QKVC + h * HD;
    bf16x8 qa0 = *(const bf16x8*)(qrow + quad * 8);
    bf16x8 qa1 = *(const bf16x8*)(qrow + 32 + quad * 8);

    f32x4 s[12] = {};
    #pragma unroll
    for (int ni = 0; ni < 12; ni++) {
        bf16x8 kb0 = *(const bf16x8*)&KsPs[(ni * 16 + lrow) * KROW + quad * 8];
        bf16x8 kb1 = *(const bf16x8*)&KsPs[(ni * 16 + lrow) * KROW + 32 + quad * 8];
        s[ni] = __builtin_amdgcn_mfma_f32_16x16x32_bf16(qa0, kb0, s[ni], 0, 0, 0);
        s[ni] = __builtin_amdgcn_mfma_f32_16x16x32_bf16(qa1, kb1, s[ni], 0, 0, 0);
    }

    bool jok[12];
    #pragma unroll
    for (int ni = 0; ni < 12; ni++) {
        int kg = base + ni * 16 + lrow;
        jok[ni] = (kg >= 0) && (kg < SS) && (amask[b * SS + (kg >= 0 && kg < SS ? kg : 0)] > 0);
    }

    const float sinkv = sinks[h];

    #pragma unroll
    for (int reg = 0; reg < 4; reg++) {
        int row = w * 16 + quad * 4 + reg;
        float mrow = -3.0e30f;
        #pragma unroll
        for (int ni = 0; ni < 12; ni++) {
            int j = ni * 16 + lrow;
            bool valid = jok[ni] && (j >= row) && (j <= row + 127);
            float val = valid ? s[ni][reg] * SCALE : -1.0e30f;
            s[ni][reg] = val;
            mrow = fmaxf(mrow, val);
        }
        #pragma unroll
        for (int off = 1; off < 16; off <<= 1) mrow = fmaxf(mrow, __shfl_xor(mrow, off));
        mrow = fmaxf(mrow, sinkv);
        float sum = 0.f;
        #pragma unroll
        for (int ni = 0; ni < 12; ni++) {
            float e = __expf(s[ni][reg] - mrow);
            s[ni][reg] = e;
            sum += e;
        }
        #pragma unroll
        for (int off = 1; off < 16; off <<= 1) sum += __shfl_xor(sum, off);
        sum += __expf(sinkv - mrow);
        float inv = 1.0f / sum;
        #pragma unroll
        for (int ni = 0; ni < 12; ni++) s[ni][reg] *= inv;
    }

    __syncthreads();

    #pragma unroll
    for (int ni = 0; ni < 12; ni++)
        #pragma unroll
        for (int reg = 0; reg < 4; reg++)
            KsPs[(w * 16 + quad * 4 + reg) * PROW + ni * 16 + lrow] =
                __hip_bfloat16(s[ni][reg]);
    __syncthreads();

    f32x4 o[4] = {};
    #pragma unroll
    for (int ks = 0; ks < 6; ks++) {
        bf16x8 pa = *(const bf16x8*)&KsPs[(w * 16 + lrow) * PROW + ks * 32 + quad * 8];
        #pragma unroll
        for (int ni = 0; ni < 4; ni++) {
            bf16x8 vb = *(const bf16x8*)&Vt[(ni * 16 + lrow) * PROW + ks * 32 + quad * 8];
            o[ni] = __builtin_amdgcn_mfma_f32_16x16x32_bf16(pa, vb, o[ni], 0, 0, 0);
        }
    }

    #pragma unroll
    for (int ni = 0; ni < 4; ni++)
        #pragma unroll
        for (int reg = 0; reg < 4; reg++) {
            int row = w * 16 + quad * 4 + reg;
            ao[((long)b * SS + q0 + row) * (NH * HD) + h * HD + ni * 16 + lrow] =
                __hip_bfloat16(o[ni][reg]);
        }
}

// ---------------------------------------------------------------------------
// Scratch plan (harness restores d_in before every launch):
//   d_out (33.5MB): xb[0:16.8M) wqkv[16.8:29.4M)   -- dead before final GEMM
//   x region (33.5MB): qkv[0:25.2M) wob[25.2:33.5M) -- x dead after prep
//   wq region (16.8MB): abuf (attn output)          -- wq dead after prep
// Order: prep -> wo-cvt -> qkv-gemm -> norm -> attn -> final gemm.
// ---------------------------------------------------------------------------
extern "C" void kernel_launch(void* const* d_in, const int* in_sizes, int n_in,
                              void* d_out, int out_size, void* d_ws, size_t ws_size,
                              hipStream_t stream) {
    const float* x     = (const float*)d_in[0];
    const int*   am    = (const int*)d_in[1];
    const float* wq    = (const float*)d_in[2];
    const float* wk    = (const float*)d_in[3];
    const float* wv    = (const float*)d_in[4];
    const float* wo    = (const float*)d_in[5];
    const float* qnw   = (const float*)d_in[6];
    const float* knw   = (const float*)d_in[7];
    const float* sinks = (const float*)d_in[8];
    float* out = (float*)d_out;

    __hip_bfloat16* xb    = (__hip_bfloat16*)d_out;
    __hip_bfloat16* wqkv  = (__hip_bfloat16*)((char*)d_out + 16777216);
    __hip_bfloat16* qkv   = (__hip_bfloat16*)x;
    __hip_bfloat16* wob   = (__hip_bfloat16*)((char*)x + 25165824);
    __hip_bfloat16* abuf  = (__hip_bfloat16*)wq;

    const long NW = (long)EMBED * EMBED;   // 4194304

    // 1. convert x + pack wq|wk|wv (7168 blocks)
    prep_cvt<<<7168, 256, 0, stream>>>(x, wq, wk, wv, xb, wqkv);
    // 2. convert wo into dead x tail
    cvt_bf16<<<NW / 2048, 256, 0, stream>>>(wo, wob, NW);

    // 3. fused QKV projection: qkv[4096][3072], 16x12 = 192 blocks
    gemm256<__hip_bfloat16, 256, 256><<<192, 512, 0, stream>>>(
        xb, wqkv, qkv, EMBED, QKVC, QKVC / 256);

    // 4. RMSNorm + RoPE on q,k inside packed qkv
    int rows = M_ROWS * NH + M_ROWS * NKV;   // 163840
    norm_rope<<<rows / 4, 256, 0, stream>>>(qkv, qnw, knw);

    // 5. attention -> abuf [4096][2048]
    attn_mfma<<<BB * NH * (SS / 64), 256, 0, stream>>>(qkv, am, sinks, abuf);

    // 6. output projection: fp32 into d_out, BM=128/BN=256, 32x8 = 256 blocks
    gemm256<float, 128, 256><<<256, 512, 0, stream>>>(
        abuf, wob, out, EMBED, EMBED, EMBED / 256);
}

// Round 5
// 289.446 us; speedup vs baseline: 1.2245x; 1.0131x over previous
//
#include <hip/hip_runtime.h>
#include <hip/hip_bf16.h>

// Problem constants. Harness: fp32 inputs, fp32 output buffer.
constexpr int BB = 2;
constexpr int SS = 2048;
constexpr int EMBED = 2048;
constexpr int NH = 32;
constexpr int NKV = 8;
constexpr int HD = 64;
constexpr int WIN = 128;
constexpr int M_ROWS = BB * SS;           // 4096
constexpr int QKVC = 3072;                // packed qkv columns
constexpr float SCALE = 0.125f;

typedef __bf16 bf16x8 __attribute__((ext_vector_type(8)));
typedef float f32x4 __attribute__((ext_vector_type(4)));

__device__ inline uint4 cvt8(float4 lo, float4 hi) {
    union { __hip_bfloat16 h[8]; uint4 u; } r;
    r.h[0] = __hip_bfloat16(lo.x); r.h[1] = __hip_bfloat16(lo.y);
    r.h[2] = __hip_bfloat16(lo.z); r.h[3] = __hip_bfloat16(lo.w);
    r.h[4] = __hip_bfloat16(hi.x); r.h[5] = __hip_bfloat16(hi.y);
    r.h[6] = __hip_bfloat16(hi.z); r.h[7] = __hip_bfloat16(hi.w);
    return r.u;
}
__device__ inline uint4 load8(const float* p) {
    float4 lo = *(const float4*)p;
    float4 hi = *(const float4*)(p + 4);
    return cvt8(lo, hi);
}

// async global->LDS, 16B per lane (wave-uniform base + lane*16).
__device__ inline void gload_lds16(const __hip_bfloat16* g, uint4* l) {
    __builtin_amdgcn_global_load_lds(
        (const __attribute__((address_space(1))) void*)g,
        (__attribute__((address_space(3))) void*)l, 16, 0, 0);
}

// ---------------------------------------------------------------------------
// prep: convert x -> xb and pack wq|wk|wv -> wqkv (bf16). 2048 elems/block.
// ---------------------------------------------------------------------------
__global__ __launch_bounds__(256) void prep_cvt(
    const float* __restrict__ x,  const float* __restrict__ wq,
    const float* __restrict__ wk, const float* __restrict__ wv,
    __hip_bfloat16* __restrict__ xb, __hip_bfloat16* __restrict__ wqkv)
{
    long bid = blockIdx.x;
    const float* src; __hip_bfloat16* dst; long off;
    if (bid < 4096)      { src = x;  dst = xb;             off = bid * 2048; }
    else if (bid < 6144) { src = wq; dst = wqkv;           off = (bid - 4096) * 2048; }
    else if (bid < 6656) { src = wk; dst = wqkv + 4194304; off = (bid - 6144) * 2048; }
    else                 { src = wv; dst = wqkv + 5242880; off = (bid - 6656) * 2048; }
    long i = off + (long)threadIdx.x * 8;
    *(uint4*)(dst + i) = load8(src + i);
}

__global__ __launch_bounds__(256) void cvt_bf16(
    const float* __restrict__ in, __hip_bfloat16* __restrict__ out, long n)
{
    long i = ((long)blockIdx.x * 256 + threadIdx.x) * 8;
    if (i + 8 <= n) *(uint4*)(out + i) = load8(in + i);
}

// ---------------------------------------------------------------------------
// BMxBN wide-phase GEMM: C[M][N] = A[M][K]·B[N][K]^T, bf16 in, TC out.
// 512 threads = 8 waves (2M x 4N); per-wave output (BM/2) x (BN/4).
// BK=64, ONE barrier per K-tile.
//
// LDS sub-buffer = [rows][8 chunks of 16B] (full BK=64 per row = 128B).
// Physical chunk (row, s_stored) holds logical k-slot s_log = s_stored ^
// (row&7)  [rule #21 both-sides]:
//  - staging dest linear (thread t -> chunk t within op); SOURCE permuted
//    within the row's 128B: thread t reads row t>>3, slot (t&7)^((t>>3)&7)
//    -> every 8 lanes cover one contiguous 128B segment (coalesced).
//  - frag read (row, quad, kstep ks): slot (ks*4+quad)^(lrow&7) ->
//    bank_start = that*4 : all 8 bank-groups x 2 lanes = conflict-free.
//    XOR is mi/wm/wn-independent (row offsets all == 0 mod 8).
//
// Schedule (T14 at tile scale): issue ALL stage-loads for tile t+1 at the
// top of tile t's body; {MI+NI ds_read -> lgkm+sched_barrier -> MI*NI MFMA}
// x 2 ksteps; vmcnt(0) (covered by the whole tile body); ONE s_barrier
// (arrival fence + overwrite protection: stages of t+1 write buf c^1,
// last read in tile t-1, sealed by t-1's barrier).
// ---------------------------------------------------------------------------
#define BAR() __builtin_amdgcn_s_barrier()
#define LGKM0() do { \
    asm volatile("s_waitcnt lgkmcnt(0)" ::: "memory"); \
    __builtin_amdgcn_sched_barrier(0); } while (0)

#define WSTAGE(NB, KOFF) do { \
    _Pragma("unroll") for (int _j = 0; _j < ALD; ++_j) \
        gload_lds16(pA + (KOFF) + _j * 64 * (long)K, \
                    (uint4*)&lds[(NB) + _j * 4096 + t * 8]); \
    _Pragma("unroll") for (int _j = 0; _j < BLD; ++_j) \
        gload_lds16(pB + (KOFF) + _j * 64 * (long)K, \
                    (uint4*)&lds[(NB) + ASUB + _j * 4096 + t * 8]); \
} while (0)

#define WPHASE(CB, XS) do { \
    _Pragma("unroll") for (int _i = 0; _i < MI; ++_i) \
        af[_i] = *(const bf16x8*)&lds[(CB) + arow0 + _i * 1024 + (XS)]; \
    _Pragma("unroll") for (int _n = 0; _n < NI; ++_n) \
        bfr[_n] = *(const bf16x8*)&lds[(CB) + ASUB + brow0 + _n * 1024 + (XS)]; \
    LGKM0(); \
    __builtin_amdgcn_s_setprio(1); \
    _Pragma("unroll") for (int _i = 0; _i < MI; ++_i) { \
        _Pragma("unroll") for (int _n = 0; _n < NI; ++_n) \
            acc[_i][_n] = __builtin_amdgcn_mfma_f32_16x16x32_bf16( \
                af[_i], bfr[_n], acc[_i][_n], 0, 0, 0); \
    } \
    __builtin_amdgcn_s_setprio(0); \
} while (0)

template <typename TC, int BM, int BN>
__global__ __launch_bounds__(512) void gemmW(
    const __hip_bfloat16* __restrict__ A,
    const __hip_bfloat16* __restrict__ Bm,
    TC* __restrict__ C, int K, int ldc, int nbx)
{
    constexpr int WN   = BN / 4;           // per-wave N span (FIX: was 64)
    constexpr int MI   = BM / 32;          // m-frags per wave
    constexpr int NI   = WN / 16;          // n-frags per wave
    constexpr int ASUB = BM * 64;          // elems per A sub-buffer
    constexpr int BSUB = BN * 64;
    constexpr int DB   = ASUB + BSUB;      // elems per buffer
    constexpr int ALD  = BM / 64;          // gload ops per A sub
    constexpr int BLD  = BN / 64;
    static_assert(WN % 16 == 0, "per-wave N must be frag-divisible");

    __shared__ __hip_bfloat16 lds[2 * DB];

    const int t = threadIdx.x;
    const int lane = t & 63;
    const int wid = t >> 6;
    const int wm = wid >> 2;                // 0..1
    const int wn = wid & 3;                 // 0..3
    const int lrow = lane & 15;
    const int quad = lane >> 4;

    // bijective XCD swizzle (nwg % 8 == 0 for both call sites)
    int bid = blockIdx.x;
    const int nwg = gridDim.x;
    if ((nwg & 7) == 0) bid = (bid & 7) * (nwg >> 3) + (bid >> 3);
    const long blockM = (long)(bid / nbx) * BM;
    const long blockN = (long)(bid % nbx) * BN;

    // staging source: thread t -> row t>>3 (+64 per op), slot (t&7)^((t>>3)&7)
    const int srow = t >> 3;
    const int sslot = ((t & 7) ^ (srow & 7)) * 8;
    const __hip_bfloat16* pA = A  + (blockM + srow) * (long)K + sslot;
    const __hip_bfloat16* pB = Bm + (blockN + srow) * (long)K + sslot;

    // frag read constants (elems); rows are 64 elems = 128B
    const int arow0 = (wm * (BM / 2) + lrow) * 64;
    const int brow0 = (wn * WN + lrow) * 64;
    const int xs0 = ((quad)     ^ (lrow & 7)) * 8;   // kstep 0
    const int xs1 = ((4 + quad) ^ (lrow & 7)) * 8;   // kstep 1

    // prologue: stage tile 0 into buf 0, drain, fence
    WSTAGE(0, 0);
    asm volatile("s_waitcnt vmcnt(0)" ::: "memory");
    BAR();

    f32x4 acc[MI][NI] = {};
    bf16x8 af[MI], bfr[NI];
    const int nkt = K >> 6;

    for (int kt = 0; kt < nkt; ++kt) {
        const int cb = (kt & 1) * DB;
        const int nb = DB - cb;
        const long kn = (long)((kt + 1 < nkt) ? (kt + 1) : kt) << 6;
        WSTAGE(nb, kn);                  // issue-early: loads for t+1
        WPHASE(cb, xs0);                 // kstep 0
        WPHASE(cb, xs1);                 // kstep 1
        asm volatile("s_waitcnt vmcnt(0)" ::: "memory");  // covered by body
        BAR();
    }

    #pragma unroll
    for (int mi = 0; mi < MI; ++mi)
        #pragma unroll
        for (int ni = 0; ni < NI; ++ni)
            #pragma unroll
            for (int r = 0; r < 4; ++r) {
                long rr = blockM + wm * (BM / 2) + mi * 16 + quad * 4 + r;
                long cc = blockN + wn * WN + ni * 16 + lrow;
                C[rr * (long)ldc + cc] = TC(acc[mi][ni][r]);
            }
}

// ---------------------------------------------------------------------------
// Per-head RMSNorm + RoPE, in place on packed qkv[row][3072].
// ---------------------------------------------------------------------------
__global__ __launch_bounds__(256) void norm_rope(
    __hip_bfloat16* __restrict__ qkv,
    const float* __restrict__ qw,
    const float* __restrict__ kw)
{
    const int QROWS = M_ROWS * NH;      // 131072
    int gid = blockIdx.x * 4 + (threadIdx.x >> 6);
    int lane = threadIdx.x & 63;

    __hip_bfloat16* base;
    const float* wptr;
    int s;
    if (gid < QROWS) {
        int row = gid >> 5;             // /NH
        base = qkv + (long)row * QKVC + (gid & 31) * HD;
        s = row % SS;
        wptr = qw;
    } else {
        int g = gid - QROWS;
        int row = g >> 3;               // /NKV
        base = qkv + (long)row * QKVC + 2048 + (g & 7) * HD;
        s = row % SS;
        wptr = kw;
    }

    float x = (float)base[lane];
    float ss = x * x;
    for (int off = 32; off; off >>= 1) ss += __shfl_xor(ss, off);
    float scale = rsqrtf(ss * (1.0f / 64.0f) + 1e-6f);
    float xn = x * scale * wptr[lane];

    float partner = __shfl_xor(xn, 32);
    int i = lane & 31;
    float ang = (float)s * powf(10000.0f, -(float)i * (1.0f / 32.0f));
    float sn, cs;
    sincosf(ang, &sn, &cs);
    float y = (lane < 32) ? (xn * cs - partner * sn) : (xn * cs + partner * sn);
    base[lane] = __hip_bfloat16(y);
}

// ---------------------------------------------------------------------------
// MFMA sliding-window attention with sink, reading packed qkv[row][3072].
// ---------------------------------------------------------------------------
constexpr int SPAN = 192;
constexpr int KROW = 72;
constexpr int PROW = 200;

__global__ __launch_bounds__(256) void attn_mfma(
    const __hip_bfloat16* __restrict__ qkv,
    const int* __restrict__ amask,
    const float* __restrict__ sinks,
    __hip_bfloat16* __restrict__ ao)     // [4096][2048] (b,s,h,d)
{
    __shared__ __hip_bfloat16 KsPs[SPAN * KROW];
    __shared__ __hip_bfloat16 Vt[64 * PROW];

    const int bid = blockIdx.x;
    const int qt = bid & 31;
    const int h = (bid >> 5) & 31;
    const int b = bid >> 10;
    const int kv = h >> 2;
    const int q0 = qt * 64;
    const int base = q0 - (WIN - 1);
    const int t = threadIdx.x;
    const int w = t >> 6;
    const int lane = t & 63;
    const int lrow = lane & 15;
    const int quad = lane >> 4;

    for (int c = t; c < SPAN * 8; c += 256) {
        int j = c >> 3;
        int d0 = (c & 7) * 8;
        int kg = base + j;
        uint4 kk = {0, 0, 0, 0}, vv = {0, 0, 0, 0};
        if (kg >= 0 && kg < SS) {
            long rowoff = ((long)b * SS + kg) * QKVC + kv * HD + d0;
            kk = *(const uint4*)(qkv + rowoff + 2048);
            vv = *(const uint4*)(qkv + rowoff + 2560);
        }
        *(uint4*)&KsPs[j * KROW + d0] = kk;
        const __hip_bfloat16* vp = (const __hip_bfloat16*)&vv;
        #pragma unroll
        for (int u = 0; u < 8; u++) Vt[(d0 + u) * PROW + j] = vp[u];
    }
    __syncthreads();

    const __hip_bfloat16* qrow =
        qkv + ((long)b * SS + q0 + w * 16 + lrow) * QKVC + h * HD;
    bf16x8 qa0 = *(const bf16x8*)(qrow + quad * 8);
    bf16x8 qa1 = *(const bf16x8*)(qrow + 32 + quad * 8);

    f32x4 s[12] = {};
    #pragma unroll
    for (int ni = 0; ni < 12; ni++) {
        bf16x8 kb0 = *(const bf16x8*)&KsPs[(ni * 16 + lrow) * KROW + quad * 8];
        bf16x8 kb1 = *(const bf16x8*)&KsPs[(ni * 16 + lrow) * KROW + 32 + quad * 8];
        s[ni] = __builtin_amdgcn_mfma_f32_16x16x32_bf16(qa0, kb0, s[ni], 0, 0, 0);
        s[ni] = __builtin_amdgcn_mfma_f32_16x16x32_bf16(qa1, kb1, s[ni], 0, 0, 0);
    }

    bool jok[12];
    #pragma unroll
    for (int ni = 0; ni < 12; ni++) {
        int kg = base + ni * 16 + lrow;
        jok[ni] = (kg >= 0) && (kg < SS) && (amask[b * SS + (kg >= 0 && kg < SS ? kg : 0)] > 0);
    }

    const float sinkv = sinks[h];

    #pragma unroll
    for (int reg = 0; reg < 4; reg++) {
        int row = w * 16 + quad * 4 + reg;
        float mrow = -3.0e30f;
        #pragma unroll
        for (int ni = 0; ni < 12; ni++) {
            int j = ni * 16 + lrow;
            bool valid = jok[ni] && (j >= row) && (j <= row + 127);
            float val = valid ? s[ni][reg] * SCALE : -1.0e30f;
            s[ni][reg] = val;
            mrow = fmaxf(mrow, val);
        }
        #pragma unroll
        for (int off = 1; off < 16; off <<= 1) mrow = fmaxf(mrow, __shfl_xor(mrow, off));
        mrow = fmaxf(mrow, sinkv);
        float sum = 0.f;
        #pragma unroll
        for (int ni = 0; ni < 12; ni++) {
            float e = __expf(s[ni][reg] - mrow);
            s[ni][reg] = e;
            sum += e;
        }
        #pragma unroll
        for (int off = 1; off < 16; off <<= 1) sum += __shfl_xor(sum, off);
        sum += __expf(sinkv - mrow);
        float inv = 1.0f / sum;
        #pragma unroll
        for (int ni = 0; ni < 12; ni++) s[ni][reg] *= inv;
    }

    __syncthreads();

    #pragma unroll
    for (int ni = 0; ni < 12; ni++)
        #pragma unroll
        for (int reg = 0; reg < 4; reg++)
            KsPs[(w * 16 + quad * 4 + reg) * PROW + ni * 16 + lrow] =
                __hip_bfloat16(s[ni][reg]);
    __syncthreads();

    f32x4 o[4] = {};
    #pragma unroll
    for (int ks = 0; ks < 6; ks++) {
        bf16x8 pa = *(const bf16x8*)&KsPs[(w * 16 + lrow) * PROW + ks * 32 + quad * 8];
        #pragma unroll
        for (int ni = 0; ni < 4; ni++) {
            bf16x8 vb = *(const bf16x8*)&Vt[(ni * 16 + lrow) * PROW + ks * 32 + quad * 8];
            o[ni] = __builtin_amdgcn_mfma_f32_16x16x32_bf16(pa, vb, o[ni], 0, 0, 0);
        }
    }

    #pragma unroll
    for (int ni = 0; ni < 4; ni++)
        #pragma unroll
        for (int reg = 0; reg < 4; reg++) {
            int row = w * 16 + quad * 4 + reg;
            ao[((long)b * SS + q0 + row) * (NH * HD) + h * HD + ni * 16 + lrow] =
                __hip_bfloat16(o[ni][reg]);
        }
}

// ---------------------------------------------------------------------------
// Scratch plan (harness restores d_in before every launch):
//   d_out (33.5MB): xb[0:16.8M) wqkv[16.8:29.4M)   -- dead before final GEMM
//   x region (33.5MB): qkv[0:25.2M) wob[25.2:33.5M) -- x dead after prep
//   wq region (16.8MB): abuf (attn output)          -- wq dead after prep
// Order: prep -> wo-cvt -> qkv-gemm -> norm -> attn -> final gemm.
// ---------------------------------------------------------------------------
extern "C" void kernel_launch(void* const* d_in, const int* in_sizes, int n_in,
                              void* d_out, int out_size, void* d_ws, size_t ws_size,
                              hipStream_t stream) {
    const float* x     = (const float*)d_in[0];
    const int*   am    = (const int*)d_in[1];
    const float* wq    = (const float*)d_in[2];
    const float* wk    = (const float*)d_in[3];
    const float* wv    = (const float*)d_in[4];
    const float* wo    = (const float*)d_in[5];
    const float* qnw   = (const float*)d_in[6];
    const float* knw   = (const float*)d_in[7];
    const float* sinks = (const float*)d_in[8];
    float* out = (float*)d_out;

    __hip_bfloat16* xb    = (__hip_bfloat16*)d_out;
    __hip_bfloat16* wqkv  = (__hip_bfloat16*)((char*)d_out + 16777216);
    __hip_bfloat16* qkv   = (__hip_bfloat16*)x;
    __hip_bfloat16* wob   = (__hip_bfloat16*)((char*)x + 25165824);
    __hip_bfloat16* abuf  = (__hip_bfloat16*)wq;

    const long NW = (long)EMBED * EMBED;   // 4194304

    // 1. convert x + pack wq|wk|wv (7168 blocks)
    prep_cvt<<<7168, 256, 0, stream>>>(x, wq, wk, wv, xb, wqkv);
    // 2. convert wo into dead x tail
    cvt_bf16<<<NW / 2048, 256, 0, stream>>>(wo, wob, NW);

    // 3. fused QKV projection: qkv[4096][3072], BM=256/BN=192, 16x16 = 256 blocks
    gemmW<__hip_bfloat16, 256, 192><<<256, 512, 0, stream>>>(
        xb, wqkv, qkv, EMBED, QKVC, QKVC / 192);

    // 4. RMSNorm + RoPE on q,k inside packed qkv
    int rows = M_ROWS * NH + M_ROWS * NKV;   // 163840
    norm_rope<<<rows / 4, 256, 0, stream>>>(qkv, qnw, knw);

    // 5. attention -> abuf [4096][2048]
    attn_mfma<<<BB * NH * (SS / 64), 256, 0, stream>>>(qkv, am, sinks, abuf);

    // 6. output projection: fp32 into d_out, BM=256/BN=128, 16x16 = 256 blocks
    gemmW<float, 256, 128><<<256, 512, 0, stream>>>(
        abuf, wob, out, EMBED, EMBED, EMBED / 128);
}

// Round 6
// 254.306 us; speedup vs baseline: 1.3937x; 1.1382x over previous
//
#include <hip/hip_runtime.h>
#include <hip/hip_bf16.h>

// Problem constants. Harness: fp32 inputs, fp32 output buffer.
constexpr int BB = 2;
constexpr int SS = 2048;
constexpr int EMBED = 2048;
constexpr int NH = 32;
constexpr int NKV = 8;
constexpr int HD = 64;
constexpr int WIN = 128;
constexpr int M_ROWS = BB * SS;           // 4096
constexpr int QKVC = 3072;                // packed qkv columns
constexpr float SCALE = 0.125f;

typedef __bf16 bf16x8 __attribute__((ext_vector_type(8)));
typedef float f32x4 __attribute__((ext_vector_type(4)));

__device__ inline uint4 cvt8(float4 lo, float4 hi) {
    union { __hip_bfloat16 h[8]; uint4 u; } r;
    r.h[0] = __hip_bfloat16(lo.x); r.h[1] = __hip_bfloat16(lo.y);
    r.h[2] = __hip_bfloat16(lo.z); r.h[3] = __hip_bfloat16(lo.w);
    r.h[4] = __hip_bfloat16(hi.x); r.h[5] = __hip_bfloat16(hi.y);
    r.h[6] = __hip_bfloat16(hi.z); r.h[7] = __hip_bfloat16(hi.w);
    return r.u;
}
__device__ inline uint4 load8(const float* p) {
    float4 lo = *(const float4*)p;
    float4 hi = *(const float4*)(p + 4);
    return cvt8(lo, hi);
}

// async global->LDS, 16B per lane (wave-uniform base + lane*16).
__device__ inline void gload_lds16(const __hip_bfloat16* g, uint4* l) {
    __builtin_amdgcn_global_load_lds(
        (const __attribute__((address_space(1))) void*)g,
        (__attribute__((address_space(3))) void*)l, 16, 0, 0);
}

// ---------------------------------------------------------------------------
// prep: convert x -> xb and pack wq|wk|wv -> wqkv (bf16). 2048 elems/block.
// ---------------------------------------------------------------------------
__global__ __launch_bounds__(256) void prep_cvt(
    const float* __restrict__ x,  const float* __restrict__ wq,
    const float* __restrict__ wk, const float* __restrict__ wv,
    __hip_bfloat16* __restrict__ xb, __hip_bfloat16* __restrict__ wqkv)
{
    long bid = blockIdx.x;
    const float* src; __hip_bfloat16* dst; long off;
    if (bid < 4096)      { src = x;  dst = xb;             off = bid * 2048; }
    else if (bid < 6144) { src = wq; dst = wqkv;           off = (bid - 4096) * 2048; }
    else if (bid < 6656) { src = wk; dst = wqkv + 4194304; off = (bid - 6144) * 2048; }
    else                 { src = wv; dst = wqkv + 5242880; off = (bid - 6656) * 2048; }
    long i = off + (long)threadIdx.x * 8;
    *(uint4*)(dst + i) = load8(src + i);
}

__global__ __launch_bounds__(256) void cvt_bf16(
    const float* __restrict__ in, __hip_bfloat16* __restrict__ out, long n)
{
    long i = ((long)blockIdx.x * 256 + threadIdx.x) * 8;
    if (i + 8 <= n) *(uint4*)(out + i) = load8(in + i);
}

// ---------------------------------------------------------------------------
// RoPE cos/sin table: tab[s][i] = (cos, sin) of s * 10000^(-i/32).
// One-time, 65536 threads; same powf/sincosf precision as the old in-line.
// ---------------------------------------------------------------------------
__global__ __launch_bounds__(256) void rope_tab(float2* __restrict__ tab) {
    int idx = blockIdx.x * 256 + threadIdx.x;   // [0, SS*32)
    int s = idx >> 5, i = idx & 31;
    float ang = (float)s * powf(10000.0f, -(float)i * (1.0f / 32.0f));
    float sn, cs;
    sincosf(ang, &sn, &cs);
    tab[idx] = make_float2(cs, sn);
}

// ---------------------------------------------------------------------------
// BMxBN wide-phase GEMM: C[M][N] = A[M][K]·B[N][K]^T, bf16 in, TC out.
// 512 threads = 8 waves (2M x 4N); per-wave output (BM/2) x (BN/4).
// BK=64, ONE barrier per K-tile.  (Schedule/layout comments: see round 5.)
// ---------------------------------------------------------------------------
#define BAR() __builtin_amdgcn_s_barrier()
#define LGKM0() do { \
    asm volatile("s_waitcnt lgkmcnt(0)" ::: "memory"); \
    __builtin_amdgcn_sched_barrier(0); } while (0)

#define WSTAGE(NB, KOFF) do { \
    _Pragma("unroll") for (int _j = 0; _j < ALD; ++_j) \
        gload_lds16(pA + (KOFF) + _j * 64 * (long)K, \
                    (uint4*)&lds[(NB) + _j * 4096 + t * 8]); \
    _Pragma("unroll") for (int _j = 0; _j < BLD; ++_j) \
        gload_lds16(pB + (KOFF) + _j * 64 * (long)K, \
                    (uint4*)&lds[(NB) + ASUB + _j * 4096 + t * 8]); \
} while (0)

#define WPHASE(CB, XS) do { \
    _Pragma("unroll") for (int _i = 0; _i < MI; ++_i) \
        af[_i] = *(const bf16x8*)&lds[(CB) + arow0 + _i * 1024 + (XS)]; \
    _Pragma("unroll") for (int _n = 0; _n < NI; ++_n) \
        bfr[_n] = *(const bf16x8*)&lds[(CB) + ASUB + brow0 + _n * 1024 + (XS)]; \
    LGKM0(); \
    __builtin_amdgcn_s_setprio(1); \
    _Pragma("unroll") for (int _i = 0; _i < MI; ++_i) { \
        _Pragma("unroll") for (int _n = 0; _n < NI; ++_n) \
            acc[_i][_n] = __builtin_amdgcn_mfma_f32_16x16x32_bf16( \
                af[_i], bfr[_n], acc[_i][_n], 0, 0, 0); \
    } \
    __builtin_amdgcn_s_setprio(0); \
} while (0)

template <typename TC, int BM, int BN>
__global__ __launch_bounds__(512) void gemmW(
    const __hip_bfloat16* __restrict__ A,
    const __hip_bfloat16* __restrict__ Bm,
    TC* __restrict__ C, int K, int ldc, int nbx)
{
    constexpr int WN   = BN / 4;           // per-wave N span
    constexpr int MI   = BM / 32;          // m-frags per wave
    constexpr int NI   = WN / 16;          // n-frags per wave
    constexpr int ASUB = BM * 64;          // elems per A sub-buffer
    constexpr int BSUB = BN * 64;
    constexpr int DB   = ASUB + BSUB;      // elems per buffer
    constexpr int ALD  = BM / 64;          // gload ops per A sub
    constexpr int BLD  = BN / 64;
    static_assert(WN % 16 == 0, "per-wave N must be frag-divisible");

    __shared__ __hip_bfloat16 lds[2 * DB];

    const int t = threadIdx.x;
    const int lane = t & 63;
    const int wid = t >> 6;
    const int wm = wid >> 2;                // 0..1
    const int wn = wid & 3;                 // 0..3
    const int lrow = lane & 15;
    const int quad = lane >> 4;

    // bijective XCD swizzle (nwg % 8 == 0 for both call sites)
    int bid = blockIdx.x;
    const int nwg = gridDim.x;
    if ((nwg & 7) == 0) bid = (bid & 7) * (nwg >> 3) + (bid >> 3);
    const long blockM = (long)(bid / nbx) * BM;
    const long blockN = (long)(bid % nbx) * BN;

    // staging source: thread t -> row t>>3 (+64 per op), slot (t&7)^((t>>3)&7)
    const int srow = t >> 3;
    const int sslot = ((t & 7) ^ (srow & 7)) * 8;
    const __hip_bfloat16* pA = A  + (blockM + srow) * (long)K + sslot;
    const __hip_bfloat16* pB = Bm + (blockN + srow) * (long)K + sslot;

    // frag read constants (elems); rows are 64 elems = 128B
    const int arow0 = (wm * (BM / 2) + lrow) * 64;
    const int brow0 = (wn * WN + lrow) * 64;
    const int xs0 = ((quad)     ^ (lrow & 7)) * 8;   // kstep 0
    const int xs1 = ((4 + quad) ^ (lrow & 7)) * 8;   // kstep 1

    // prologue: stage tile 0 into buf 0, drain, fence
    WSTAGE(0, 0);
    asm volatile("s_waitcnt vmcnt(0)" ::: "memory");
    BAR();

    f32x4 acc[MI][NI] = {};
    bf16x8 af[MI], bfr[NI];
    const int nkt = K >> 6;

    for (int kt = 0; kt < nkt; ++kt) {
        const int cb = (kt & 1) * DB;
        const int nb = DB - cb;
        const long kn = (long)((kt + 1 < nkt) ? (kt + 1) : kt) << 6;
        WSTAGE(nb, kn);                  // issue-early: loads for t+1
        WPHASE(cb, xs0);                 // kstep 0
        WPHASE(cb, xs1);                 // kstep 1
        asm volatile("s_waitcnt vmcnt(0)" ::: "memory");  // covered by body
        BAR();
    }

    #pragma unroll
    for (int mi = 0; mi < MI; ++mi)
        #pragma unroll
        for (int ni = 0; ni < NI; ++ni)
            #pragma unroll
            for (int r = 0; r < 4; ++r) {
                long rr = blockM + wm * (BM / 2) + mi * 16 + quad * 4 + r;
                long cc = blockN + wn * WN + ni * 16 + lrow;
                C[rr * (long)ldc + cc] = TC(acc[mi][ni][r]);
            }
}

// ---------------------------------------------------------------------------
// Per-head RMSNorm + RoPE v2, in place on packed qkv[row][3072].
// 8 threads per head-row (16B/lane); RMS reduce = 3 shfl_xor within the
// 8-lane group; RoPE partner (i <-> i+32) via shfl_xor(.,4); cos/sin from
// the precomputed table (kills the per-element powf/sincosf VALU chain).
// ---------------------------------------------------------------------------
__global__ __launch_bounds__(256) void norm_rope(
    __hip_bfloat16* __restrict__ qkv,
    const float* __restrict__ qw,
    const float* __restrict__ kw,
    const float2* __restrict__ tab)      // [SS][32]
{
    const int QROWS = M_ROWS * NH;      // 131072
    const int lane = threadIdx.x & 63;
    const int sub = lane >> 3;           // head-row within wave (0..7)
    const int j = lane & 7;              // 8-elem chunk within row (0..7)
    const int gid = (blockIdx.x * 4 + (threadIdx.x >> 6)) * 8 + sub;

    __hip_bfloat16* base;
    const float* wptr;
    int s;
    if (gid < QROWS) {
        int row = gid >> 5;             // /NH
        base = qkv + (long)row * QKVC + (gid & 31) * HD;
        s = row & (SS - 1);
        wptr = qw;
    } else {
        int g = gid - QROWS;
        int row = g >> 3;               // /NKV
        base = qkv + (long)row * QKVC + 2048 + (g & 7) * HD;
        s = row & (SS - 1);
        wptr = kw;
    }

    bf16x8 v = *(const bf16x8*)(base + j * 8);
    float xf[8];
    float ss = 0.f;
    #pragma unroll
    for (int u = 0; u < 8; ++u) { xf[u] = (float)v[u]; ss += xf[u] * xf[u]; }
    ss += __shfl_xor(ss, 1); ss += __shfl_xor(ss, 2); ss += __shfl_xor(ss, 4);
    float scale = rsqrtf(ss * (1.0f / 64.0f) + 1e-6f);
    #pragma unroll
    for (int u = 0; u < 8; ++u) xf[u] = xf[u] * scale * wptr[j * 8 + u];

    // partner pack: thread j<4 holds i=j*8+u, thread j^4 holds i+32
    float pf[8];
    #pragma unroll
    for (int u = 0; u < 8; ++u) pf[u] = __shfl_xor(xf[u], 4);

    const float2* tp = tab + s * 32 + (j & 3) * 8;
    union { __hip_bfloat16 h[8]; uint4 u4; } y;
    #pragma unroll
    for (int u = 0; u < 8; ++u) {
        float2 cs2 = tp[u];
        float yv = (j < 4) ? (xf[u] * cs2.x - pf[u] * cs2.y)
                           : (xf[u] * cs2.x + pf[u] * cs2.y);
        y.h[u] = __hip_bfloat16(yv);
    }
    *(uint4*)(base + j * 8) = y.u4;
}

// ---------------------------------------------------------------------------
// MFMA sliding-window attention with sink, reading packed qkv[row][3072].
// ---------------------------------------------------------------------------
constexpr int SPAN = 192;
constexpr int KROW = 72;
constexpr int PROW = 200;

__global__ __launch_bounds__(256) void attn_mfma(
    const __hip_bfloat16* __restrict__ qkv,
    const int* __restrict__ amask,
    const float* __restrict__ sinks,
    __hip_bfloat16* __restrict__ ao)     // [4096][2048] (b,s,h,d)
{
    __shared__ __hip_bfloat16 KsPs[SPAN * KROW];
    __shared__ __hip_bfloat16 Vt[64 * PROW];

    const int bid = blockIdx.x;
    const int qt = bid & 31;
    const int h = (bid >> 5) & 31;
    const int b = bid >> 10;
    const int kv = h >> 2;
    const int q0 = qt * 64;
    const int base = q0 - (WIN - 1);
    const int t = threadIdx.x;
    const int w = t >> 6;
    const int lane = t & 63;
    const int lrow = lane & 15;
    const int quad = lane >> 4;

    for (int c = t; c < SPAN * 8; c += 256) {
        int j = c >> 3;
        int d0 = (c & 7) * 8;
        int kg = base + j;
        uint4 kk = {0, 0, 0, 0}, vv = {0, 0, 0, 0};
        if (kg >= 0 && kg < SS) {
            long rowoff = ((long)b * SS + kg) * QKVC + kv * HD + d0;
            kk = *(const uint4*)(qkv + rowoff + 2048);
            vv = *(const uint4*)(qkv + rowoff + 2560);
        }
        *(uint4*)&KsPs[j * KROW + d0] = kk;
        const __hip_bfloat16* vp = (const __hip_bfloat16*)&vv;
        #pragma unroll
        for (int u = 0; u < 8; u++) Vt[(d0 + u) * PROW + j] = vp[u];
    }
    __syncthreads();

    const __hip_bfloat16* qrow =
        qkv + ((long)b * SS + q0 + w * 16 + lrow) * QKVC + h * HD;
    bf16x8 qa0 = *(const bf16x8*)(qrow + quad * 8);
    bf16x8 qa1 = *(const bf16x8*)(qrow + 32 + quad * 8);

    f32x4 s[12] = {};
    #pragma unroll
    for (int ni = 0; ni < 12; ni++) {
        bf16x8 kb0 = *(const bf16x8*)&KsPs[(ni * 16 + lrow) * KROW + quad * 8];
        bf16x8 kb1 = *(const bf16x8*)&KsPs[(ni * 16 + lrow) * KROW + 32 + quad * 8];
        s[ni] = __builtin_amdgcn_mfma_f32_16x16x32_bf16(qa0, kb0, s[ni], 0, 0, 0);
        s[ni] = __builtin_amdgcn_mfma_f32_16x16x32_bf16(qa1, kb1, s[ni], 0, 0, 0);
    }

    bool jok[12];
    #pragma unroll
    for (int ni = 0; ni < 12; ni++) {
        int kg = base + ni * 16 + lrow;
        jok[ni] = (kg >= 0) && (kg < SS) && (amask[b * SS + (kg >= 0 && kg < SS ? kg : 0)] > 0);
    }

    const float sinkv = sinks[h];

    #pragma unroll
    for (int reg = 0; reg < 4; reg++) {
        int row = w * 16 + quad * 4 + reg;
        float mrow = -3.0e30f;
        #pragma unroll
        for (int ni = 0; ni < 12; ni++) {
            int j = ni * 16 + lrow;
            bool valid = jok[ni] && (j >= row) && (j <= row + 127);
            float val = valid ? s[ni][reg] * SCALE : -1.0e30f;
            s[ni][reg] = val;
            mrow = fmaxf(mrow, val);
        }
        #pragma unroll
        for (int off = 1; off < 16; off <<= 1) mrow = fmaxf(mrow, __shfl_xor(mrow, off));
        mrow = fmaxf(mrow, sinkv);
        float sum = 0.f;
        #pragma unroll
        for (int ni = 0; ni < 12; ni++) {
            float e = __expf(s[ni][reg] - mrow);
            s[ni][reg] = e;
            sum += e;
        }
        #pragma unroll
        for (int off = 1; off < 16; off <<= 1) sum += __shfl_xor(sum, off);
        sum += __expf(sinkv - mrow);
        float inv = 1.0f / sum;
        #pragma unroll
        for (int ni = 0; ni < 12; ni++) s[ni][reg] *= inv;
    }

    __syncthreads();

    #pragma unroll
    for (int ni = 0; ni < 12; ni++)
        #pragma unroll
        for (int reg = 0; reg < 4; reg++)
            KsPs[(w * 16 + quad * 4 + reg) * PROW + ni * 16 + lrow] =
                __hip_bfloat16(s[ni][reg]);
    __syncthreads();

    f32x4 o[4] = {};
    #pragma unroll
    for (int ks = 0; ks < 6; ks++) {
        bf16x8 pa = *(const bf16x8*)&KsPs[(w * 16 + lrow) * PROW + ks * 32 + quad * 8];
        #pragma unroll
        for (int ni = 0; ni < 4; ni++) {
            bf16x8 vb = *(const bf16x8*)&Vt[(ni * 16 + lrow) * PROW + ks * 32 + quad * 8];
            o[ni] = __builtin_amdgcn_mfma_f32_16x16x32_bf16(pa, vb, o[ni], 0, 0, 0);
        }
    }

    #pragma unroll
    for (int ni = 0; ni < 4; ni++)
        #pragma unroll
        for (int reg = 0; reg < 4; reg++) {
            int row = w * 16 + quad * 4 + reg;
            ao[((long)b * SS + q0 + row) * (NH * HD) + h * HD + ni * 16 + lrow] =
                __hip_bfloat16(o[ni][reg]);
        }
}

// ---------------------------------------------------------------------------
// Scratch plan (harness restores d_in before every launch):
//   d_out (33.5MB): xb[0:16.8M) wqkv[16.8:29.36M) ropetab[29.36:29.88M)
//                   -- all dead before final GEMM overwrites d_out
//   x region (33.5MB): qkv[0:25.2M) wob[25.2:33.5M) -- x dead after prep
//   wq region (16.8MB): abuf (attn output)          -- wq dead after prep
// Order: prep -> rope_tab -> wo-cvt -> qkv-gemm -> norm -> attn -> final gemm.
// ---------------------------------------------------------------------------
extern "C" void kernel_launch(void* const* d_in, const int* in_sizes, int n_in,
                              void* d_out, int out_size, void* d_ws, size_t ws_size,
                              hipStream_t stream) {
    const float* x     = (const float*)d_in[0];
    const int*   am    = (const int*)d_in[1];
    const float* wq    = (const float*)d_in[2];
    const float* wk    = (const float*)d_in[3];
    const float* wv    = (const float*)d_in[4];
    const float* wo    = (const float*)d_in[5];
    const float* qnw   = (const float*)d_in[6];
    const float* knw   = (const float*)d_in[7];
    const float* sinks = (const float*)d_in[8];
    float* out = (float*)d_out;

    __hip_bfloat16* xb    = (__hip_bfloat16*)d_out;
    __hip_bfloat16* wqkv  = (__hip_bfloat16*)((char*)d_out + 16777216);
    float2*         rtab  = (float2*)((char*)d_out + 29360128);
    __hip_bfloat16* qkv   = (__hip_bfloat16*)x;
    __hip_bfloat16* wob   = (__hip_bfloat16*)((char*)x + 25165824);
    __hip_bfloat16* abuf  = (__hip_bfloat16*)wq;

    const long NW = (long)EMBED * EMBED;   // 4194304

    // 1. convert x + pack wq|wk|wv (7168 blocks)
    prep_cvt<<<7168, 256, 0, stream>>>(x, wq, wk, wv, xb, wqkv);
    // 1b. RoPE cos/sin table (65536 entries)
    rope_tab<<<SS * 32 / 256, 256, 0, stream>>>(rtab);
    // 2. convert wo into dead x tail
    cvt_bf16<<<NW / 2048, 256, 0, stream>>>(wo, wob, NW);

    // 3. fused QKV projection: qkv[4096][3072], BM=256/BN=192, 16x16 = 256 blocks
    gemmW<__hip_bfloat16, 256, 192><<<256, 512, 0, stream>>>(
        xb, wqkv, qkv, EMBED, QKVC, QKVC / 192);

    // 4. RMSNorm + RoPE on q,k inside packed qkv (8 rows/wave, table-driven)
    int rows = M_ROWS * NH + M_ROWS * NKV;   // 163840
    norm_rope<<<rows / 32, 256, 0, stream>>>(qkv, qnw, knw, rtab);

    // 5. attention -> abuf [4096][2048]
    attn_mfma<<<BB * NH * (SS / 64), 256, 0, stream>>>(qkv, am, sinks, abuf);

    // 6. output projection: fp32 into d_out, BM=256/BN=128, 16x16 = 256 blocks
    gemmW<float, 256, 128><<<256, 512, 0, stream>>>(
        abuf, wob, out, EMBED, EMBED, EMBED / 128);
}

// Round 7
// 252.139 us; speedup vs baseline: 1.4056x; 1.0086x over previous
//
#include <hip/hip_runtime.h>
#include <hip/hip_bf16.h>

// Problem constants. Harness: fp32 inputs, fp32 output buffer.
constexpr int BB = 2;
constexpr int SS = 2048;
constexpr int EMBED = 2048;
constexpr int NH = 32;
constexpr int NKV = 8;
constexpr int HD = 64;
constexpr int WIN = 128;
constexpr int M_ROWS = BB * SS;           // 4096
constexpr int QKVC = 3072;                // packed qkv columns
constexpr float SCALE = 0.125f;

typedef __bf16 bf16x8 __attribute__((ext_vector_type(8)));
typedef float f32x4 __attribute__((ext_vector_type(4)));

__device__ inline uint4 cvt8(float4 lo, float4 hi) {
    union { __hip_bfloat16 h[8]; uint4 u; } r;
    r.h[0] = __hip_bfloat16(lo.x); r.h[1] = __hip_bfloat16(lo.y);
    r.h[2] = __hip_bfloat16(lo.z); r.h[3] = __hip_bfloat16(lo.w);
    r.h[4] = __hip_bfloat16(hi.x); r.h[5] = __hip_bfloat16(hi.y);
    r.h[6] = __hip_bfloat16(hi.z); r.h[7] = __hip_bfloat16(hi.w);
    return r.u;
}
__device__ inline uint4 load8(const float* p) {
    float4 lo = *(const float4*)p;
    float4 hi = *(const float4*)(p + 4);
    return cvt8(lo, hi);
}

// async global->LDS, 16B per lane (wave-uniform base + lane*16).
__device__ inline void gload_lds16(const __hip_bfloat16* g, uint4* l) {
    __builtin_amdgcn_global_load_lds(
        (const __attribute__((address_space(1))) void*)g,
        (__attribute__((address_space(3))) void*)l, 16, 0, 0);
}

// ---------------------------------------------------------------------------
// prep: convert x -> xb and pack wq|wk|wv -> wqkv (bf16). 2048 elems/block.
// ---------------------------------------------------------------------------
__global__ __launch_bounds__(256) void prep_cvt(
    const float* __restrict__ x,  const float* __restrict__ wq,
    const float* __restrict__ wk, const float* __restrict__ wv,
    __hip_bfloat16* __restrict__ xb, __hip_bfloat16* __restrict__ wqkv)
{
    long bid = blockIdx.x;
    const float* src; __hip_bfloat16* dst; long off;
    if (bid < 4096)      { src = x;  dst = xb;             off = bid * 2048; }
    else if (bid < 6144) { src = wq; dst = wqkv;           off = (bid - 4096) * 2048; }
    else if (bid < 6656) { src = wk; dst = wqkv + 4194304; off = (bid - 6144) * 2048; }
    else                 { src = wv; dst = wqkv + 5242880; off = (bid - 6656) * 2048; }
    long i = off + (long)threadIdx.x * 8;
    *(uint4*)(dst + i) = load8(src + i);
}

__global__ __launch_bounds__(256) void cvt_bf16(
    const float* __restrict__ in, __hip_bfloat16* __restrict__ out, long n)
{
    long i = ((long)blockIdx.x * 256 + threadIdx.x) * 8;
    if (i + 8 <= n) *(uint4*)(out + i) = load8(in + i);
}

// ---------------------------------------------------------------------------
// RoPE cos/sin table: tab[s][i] = (cos, sin) of s * 10000^(-i/32).
// ---------------------------------------------------------------------------
__global__ __launch_bounds__(256) void rope_tab(float2* __restrict__ tab) {
    int idx = blockIdx.x * 256 + threadIdx.x;   // [0, SS*32)
    int s = idx >> 5, i = idx & 31;
    float ang = (float)s * powf(10000.0f, -(float)i * (1.0f / 32.0f));
    float sn, cs;
    sincosf(ang, &sn, &cs);
    tab[idx] = make_float2(cs, sn);
}

// ---------------------------------------------------------------------------
// BMxBN wide-phase GEMM v2: C[M][N] = A[M][K]·B[N][K]^T, bf16 in, TC out.
// 512 threads = 8 waves (2M x 4N); per-wave output (BM/2) x (BN/4).
// BK=64, ONE barrier per K-tile.
//
// v2 change (intra-tile pipeline via counted lgkmcnt): issue ALL 2*NRD frag
// ds_reads up front (kstep0's NRD first, then kstep1's), wait lgkmcnt(NRD)
// (DS retires in order -> kstep0 ready), MFMA kstep0 WHILE kstep1's reads
// are in flight, lgkmcnt(0), MFMA kstep1. This overlaps the ~88KB/CU LDS
// read phase with the matrix pipe instead of serializing them (the round-6
// 39% MfmaUtil ceiling). sched_barrier(0) after each wait per rule #18.
//
// LDS layout + staging (rule #21 both-sides XOR) unchanged from round 5:
// sub-buffer [rows][8x16B chunks], chunk (row,s) holds slot s^(row&7);
// staging source permuted within each row's 128B (coalesced), dest linear;
// frag read slot (ks*4+quad)^(lrow&7) -> all 8 bank-groups x 2 lanes.
// ---------------------------------------------------------------------------
#define BAR() __builtin_amdgcn_s_barrier()

#define WSTAGE(NB, KOFF) do { \
    _Pragma("unroll") for (int _j = 0; _j < ALD; ++_j) \
        gload_lds16(pA + (KOFF) + _j * 64 * (long)K, \
                    (uint4*)&lds[(NB) + _j * 4096 + t * 8]); \
    _Pragma("unroll") for (int _j = 0; _j < BLD; ++_j) \
        gload_lds16(pB + (KOFF) + _j * 64 * (long)K, \
                    (uint4*)&lds[(NB) + ASUB + _j * 4096 + t * 8]); \
} while (0)

#define WREAD(CB, XS, AF, BF) do { \
    _Pragma("unroll") for (int _i = 0; _i < MI; ++_i) \
        AF[_i] = *(const bf16x8*)&lds[(CB) + arow0 + _i * 1024 + (XS)]; \
    _Pragma("unroll") for (int _n = 0; _n < NI; ++_n) \
        BF[_n] = *(const bf16x8*)&lds[(CB) + ASUB + brow0 + _n * 1024 + (XS)]; \
} while (0)

#define WMMA(AF, BF) do { \
    __builtin_amdgcn_s_setprio(1); \
    _Pragma("unroll") for (int _i = 0; _i < MI; ++_i) { \
        _Pragma("unroll") for (int _n = 0; _n < NI; ++_n) \
            acc[_i][_n] = __builtin_amdgcn_mfma_f32_16x16x32_bf16( \
                AF[_i], BF[_n], acc[_i][_n], 0, 0, 0); \
    } \
    __builtin_amdgcn_s_setprio(0); \
} while (0)

#define LGKM_N() do { \
    if constexpr (NRD == 11)      asm volatile("s_waitcnt lgkmcnt(11)" ::: "memory"); \
    else if constexpr (NRD == 10) asm volatile("s_waitcnt lgkmcnt(10)" ::: "memory"); \
    else                          asm volatile("s_waitcnt lgkmcnt(0)"  ::: "memory"); \
    __builtin_amdgcn_sched_barrier(0); } while (0)

#define LGKM_0() do { \
    asm volatile("s_waitcnt lgkmcnt(0)" ::: "memory"); \
    __builtin_amdgcn_sched_barrier(0); } while (0)

template <typename TC, int BM, int BN>
__global__ __launch_bounds__(512) void gemmW(
    const __hip_bfloat16* __restrict__ A,
    const __hip_bfloat16* __restrict__ Bm,
    TC* __restrict__ C, int K, int ldc, int nbx)
{
    constexpr int WN   = BN / 4;           // per-wave N span
    constexpr int MI   = BM / 32;          // m-frags per wave
    constexpr int NI   = WN / 16;          // n-frags per wave
    constexpr int NRD  = MI + NI;          // frag ds_reads per kstep
    constexpr int ASUB = BM * 64;          // elems per A sub-buffer
    constexpr int BSUB = BN * 64;
    constexpr int DB   = ASUB + BSUB;      // elems per buffer
    constexpr int ALD  = BM / 64;          // gload ops per A sub
    constexpr int BLD  = BN / 64;
    static_assert(WN % 16 == 0, "per-wave N must be frag-divisible");

    __shared__ __hip_bfloat16 lds[2 * DB];

    const int t = threadIdx.x;
    const int lane = t & 63;
    const int wid = t >> 6;
    const int wm = wid >> 2;                // 0..1
    const int wn = wid & 3;                 // 0..3
    const int lrow = lane & 15;
    const int quad = lane >> 4;

    // bijective XCD swizzle (nwg % 8 == 0 for both call sites)
    int bid = blockIdx.x;
    const int nwg = gridDim.x;
    if ((nwg & 7) == 0) bid = (bid & 7) * (nwg >> 3) + (bid >> 3);
    const long blockM = (long)(bid / nbx) * BM;
    const long blockN = (long)(bid % nbx) * BN;

    // staging source: thread t -> row t>>3 (+64 per op), slot (t&7)^((t>>3)&7)
    const int srow = t >> 3;
    const int sslot = ((t & 7) ^ (srow & 7)) * 8;
    const __hip_bfloat16* pA = A  + (blockM + srow) * (long)K + sslot;
    const __hip_bfloat16* pB = Bm + (blockN + srow) * (long)K + sslot;

    // frag read constants (elems); rows are 64 elems = 128B
    const int arow0 = (wm * (BM / 2) + lrow) * 64;
    const int brow0 = (wn * WN + lrow) * 64;
    const int xs0 = ((quad)     ^ (lrow & 7)) * 8;   // kstep 0
    const int xs1 = ((4 + quad) ^ (lrow & 7)) * 8;   // kstep 1

    // prologue: stage tile 0 into buf 0, drain, fence
    WSTAGE(0, 0);
    asm volatile("s_waitcnt vmcnt(0)" ::: "memory");
    BAR();

    f32x4 acc[MI][NI] = {};
    bf16x8 af0[MI], af1[MI], bf0[NI], bf1[NI];
    const int nkt = K >> 6;

    for (int kt = 0; kt < nkt; ++kt) {
        const int cb = (kt & 1) * DB;
        const int nb = DB - cb;
        const long kn = (long)((kt + 1 < nkt) ? (kt + 1) : kt) << 6;
        WSTAGE(nb, kn);                  // issue-early: loads for t+1
        WREAD(cb, xs0, af0, bf0);        // kstep0 frag reads (oldest NRD)
        WREAD(cb, xs1, af1, bf1);        // kstep1 frag reads
        LGKM_N();                        // wait kstep0 only
        WMMA(af0, bf0);                  // MFMA k0 || ds_read k1 in flight
        LGKM_0();
        WMMA(af1, bf1);
        asm volatile("s_waitcnt vmcnt(0)" ::: "memory");  // covered by body
        BAR();
    }

    #pragma unroll
    for (int mi = 0; mi < MI; ++mi)
        #pragma unroll
        for (int ni = 0; ni < NI; ++ni)
            #pragma unroll
            for (int r = 0; r < 4; ++r) {
                long rr = blockM + wm * (BM / 2) + mi * 16 + quad * 4 + r;
                long cc = blockN + wn * WN + ni * 16 + lrow;
                C[rr * (long)ldc + cc] = TC(acc[mi][ni][r]);
            }
}

// ---------------------------------------------------------------------------
// Per-head RMSNorm + RoPE v2, in place on packed qkv[row][3072].
// 8 threads per head-row (16B/lane); table-driven cos/sin.
// ---------------------------------------------------------------------------
__global__ __launch_bounds__(256) void norm_rope(
    __hip_bfloat16* __restrict__ qkv,
    const float* __restrict__ qw,
    const float* __restrict__ kw,
    const float2* __restrict__ tab)      // [SS][32]
{
    const int QROWS = M_ROWS * NH;      // 131072
    const int lane = threadIdx.x & 63;
    const int sub = lane >> 3;           // head-row within wave (0..7)
    const int j = lane & 7;              // 8-elem chunk within row (0..7)
    const int gid = (blockIdx.x * 4 + (threadIdx.x >> 6)) * 8 + sub;

    __hip_bfloat16* base;
    const float* wptr;
    int s;
    if (gid < QROWS) {
        int row = gid >> 5;             // /NH
        base = qkv + (long)row * QKVC + (gid & 31) * HD;
        s = row & (SS - 1);
        wptr = qw;
    } else {
        int g = gid - QROWS;
        int row = g >> 3;               // /NKV
        base = qkv + (long)row * QKVC + 2048 + (g & 7) * HD;
        s = row & (SS - 1);
        wptr = kw;
    }

    bf16x8 v = *(const bf16x8*)(base + j * 8);
    float xf[8];
    float ss = 0.f;
    #pragma unroll
    for (int u = 0; u < 8; ++u) { xf[u] = (float)v[u]; ss += xf[u] * xf[u]; }
    ss += __shfl_xor(ss, 1); ss += __shfl_xor(ss, 2); ss += __shfl_xor(ss, 4);
    float scale = rsqrtf(ss * (1.0f / 64.0f) + 1e-6f);
    #pragma unroll
    for (int u = 0; u < 8; ++u) xf[u] = xf[u] * scale * wptr[j * 8 + u];

    // partner pack: thread j<4 holds i=j*8+u, thread j^4 holds i+32
    float pf[8];
    #pragma unroll
    for (int u = 0; u < 8; ++u) pf[u] = __shfl_xor(xf[u], 4);

    const float2* tp = tab + s * 32 + (j & 3) * 8;
    union { __hip_bfloat16 h[8]; uint4 u4; } y;
    #pragma unroll
    for (int u = 0; u < 8; ++u) {
        float2 cs2 = tp[u];
        float yv = (j < 4) ? (xf[u] * cs2.x - pf[u] * cs2.y)
                           : (xf[u] * cs2.x + pf[u] * cs2.y);
        y.h[u] = __hip_bfloat16(yv);
    }
    *(uint4*)(base + j * 8) = y.u4;
}

// ---------------------------------------------------------------------------
// MFMA sliding-window attention with sink, reading packed qkv[row][3072].
// ---------------------------------------------------------------------------
constexpr int SPAN = 192;
constexpr int KROW = 72;
constexpr int PROW = 200;

__global__ __launch_bounds__(256) void attn_mfma(
    const __hip_bfloat16* __restrict__ qkv,
    const int* __restrict__ amask,
    const float* __restrict__ sinks,
    __hip_bfloat16* __restrict__ ao)     // [4096][2048] (b,s,h,d)
{
    __shared__ __hip_bfloat16 KsPs[SPAN * KROW];
    __shared__ __hip_bfloat16 Vt[64 * PROW];

    const int bid = blockIdx.x;
    const int qt = bid & 31;
    const int h = (bid >> 5) & 31;
    const int b = bid >> 10;
    const int kv = h >> 2;
    const int q0 = qt * 64;
    const int base = q0 - (WIN - 1);
    const int t = threadIdx.x;
    const int w = t >> 6;
    const int lane = t & 63;
    const int lrow = lane & 15;
    const int quad = lane >> 4;

    for (int c = t; c < SPAN * 8; c += 256) {
        int j = c >> 3;
        int d0 = (c & 7) * 8;
        int kg = base + j;
        uint4 kk = {0, 0, 0, 0}, vv = {0, 0, 0, 0};
        if (kg >= 0 && kg < SS) {
            long rowoff = ((long)b * SS + kg) * QKVC + kv * HD + d0;
            kk = *(const uint4*)(qkv + rowoff + 2048);
            vv = *(const uint4*)(qkv + rowoff + 2560);
        }
        *(uint4*)&KsPs[j * KROW + d0] = kk;
        const __hip_bfloat16* vp = (const __hip_bfloat16*)&vv;
        #pragma unroll
        for (int u = 0; u < 8; u++) Vt[(d0 + u) * PROW + j] = vp[u];
    }
    __syncthreads();

    const __hip_bfloat16* qrow =
        qkv + ((long)b * SS + q0 + w * 16 + lrow) * QKVC + h * HD;
    bf16x8 qa0 = *(const bf16x8*)(qrow + quad * 8);
    bf16x8 qa1 = *(const bf16x8*)(qrow + 32 + quad * 8);

    f32x4 s[12] = {};
    #pragma unroll
    for (int ni = 0; ni < 12; ni++) {
        bf16x8 kb0 = *(const bf16x8*)&KsPs[(ni * 16 + lrow) * KROW + quad * 8];
        bf16x8 kb1 = *(const bf16x8*)&KsPs[(ni * 16 + lrow) * KROW + 32 + quad * 8];
        s[ni] = __builtin_amdgcn_mfma_f32_16x16x32_bf16(qa0, kb0, s[ni], 0, 0, 0);
        s[ni] = __builtin_amdgcn_mfma_f32_16x16x32_bf16(qa1, kb1, s[ni], 0, 0, 0);
    }

    bool jok[12];
    #pragma unroll
    for (int ni = 0; ni < 12; ni++) {
        int kg = base + ni * 16 + lrow;
        jok[ni] = (kg >= 0) && (kg < SS) && (amask[b * SS + (kg >= 0 && kg < SS ? kg : 0)] > 0);
    }

    const float sinkv = sinks[h];

    #pragma unroll
    for (int reg = 0; reg < 4; reg++) {
        int row = w * 16 + quad * 4 + reg;
        float mrow = -3.0e30f;
        #pragma unroll
        for (int ni = 0; ni < 12; ni++) {
            int j = ni * 16 + lrow;
            bool valid = jok[ni] && (j >= row) && (j <= row + 127);
            float val = valid ? s[ni][reg] * SCALE : -1.0e30f;
            s[ni][reg] = val;
            mrow = fmaxf(mrow, val);
        }
        #pragma unroll
        for (int off = 1; off < 16; off <<= 1) mrow = fmaxf(mrow, __shfl_xor(mrow, off));
        mrow = fmaxf(mrow, sinkv);
        float sum = 0.f;
        #pragma unroll
        for (int ni = 0; ni < 12; ni++) {
            float e = __expf(s[ni][reg] - mrow);
            s[ni][reg] = e;
            sum += e;
        }
        #pragma unroll
        for (int off = 1; off < 16; off <<= 1) sum += __shfl_xor(sum, off);
        sum += __expf(sinkv - mrow);
        float inv = 1.0f / sum;
        #pragma unroll
        for (int ni = 0; ni < 12; ni++) s[ni][reg] *= inv;
    }

    __syncthreads();

    #pragma unroll
    for (int ni = 0; ni < 12; ni++)
        #pragma unroll
        for (int reg = 0; reg < 4; reg++)
            KsPs[(w * 16 + quad * 4 + reg) * PROW + ni * 16 + lrow] =
                __hip_bfloat16(s[ni][reg]);
    __syncthreads();

    f32x4 o[4] = {};
    #pragma unroll
    for (int ks = 0; ks < 6; ks++) {
        bf16x8 pa = *(const bf16x8*)&KsPs[(w * 16 + lrow) * PROW + ks * 32 + quad * 8];
        #pragma unroll
        for (int ni = 0; ni < 4; ni++) {
            bf16x8 vb = *(const bf16x8*)&Vt[(ni * 16 + lrow) * PROW + ks * 32 + quad * 8];
            o[ni] = __builtin_amdgcn_mfma_f32_16x16x32_bf16(pa, vb, o[ni], 0, 0, 0);
        }
    }

    #pragma unroll
    for (int ni = 0; ni < 4; ni++)
        #pragma unroll
        for (int reg = 0; reg < 4; reg++) {
            int row = w * 16 + quad * 4 + reg;
            ao[((long)b * SS + q0 + row) * (NH * HD) + h * HD + ni * 16 + lrow] =
                __hip_bfloat16(o[ni][reg]);
        }
}

// ---------------------------------------------------------------------------
// Scratch plan (harness restores d_in before every launch):
//   d_out (33.5MB): xb[0:16.8M) wqkv[16.8:29.36M) ropetab[29.36:29.88M)
//                   -- all dead before final GEMM overwrites d_out
//   x region (33.5MB): qkv[0:25.2M) wob[25.2:33.5M) -- x dead after prep
//   wq region (16.8MB): abuf (attn output)          -- wq dead after prep
// Order: prep -> rope_tab -> wo-cvt -> qkv-gemm -> norm -> attn -> final gemm.
// ---------------------------------------------------------------------------
extern "C" void kernel_launch(void* const* d_in, const int* in_sizes, int n_in,
                              void* d_out, int out_size, void* d_ws, size_t ws_size,
                              hipStream_t stream) {
    const float* x     = (const float*)d_in[0];
    const int*   am    = (const int*)d_in[1];
    const float* wq    = (const float*)d_in[2];
    const float* wk    = (const float*)d_in[3];
    const float* wv    = (const float*)d_in[4];
    const float* wo    = (const float*)d_in[5];
    const float* qnw   = (const float*)d_in[6];
    const float* knw   = (const float*)d_in[7];
    const float* sinks = (const float*)d_in[8];
    float* out = (float*)d_out;

    __hip_bfloat16* xb    = (__hip_bfloat16*)d_out;
    __hip_bfloat16* wqkv  = (__hip_bfloat16*)((char*)d_out + 16777216);
    float2*         rtab  = (float2*)((char*)d_out + 29360128);
    __hip_bfloat16* qkv   = (__hip_bfloat16*)x;
    __hip_bfloat16* wob   = (__hip_bfloat16*)((char*)x + 25165824);
    __hip_bfloat16* abuf  = (__hip_bfloat16*)wq;

    const long NW = (long)EMBED * EMBED;   // 4194304

    // 1. convert x + pack wq|wk|wv (7168 blocks)
    prep_cvt<<<7168, 256, 0, stream>>>(x, wq, wk, wv, xb, wqkv);
    // 1b. RoPE cos/sin table (65536 entries)
    rope_tab<<<SS * 32 / 256, 256, 0, stream>>>(rtab);
    // 2. convert wo into dead x tail
    cvt_bf16<<<NW / 2048, 256, 0, stream>>>(wo, wob, NW);

    // 3. fused QKV projection: qkv[4096][3072], BM=256/BN=192, 16x16 = 256 blocks
    gemmW<__hip_bfloat16, 256, 192><<<256, 512, 0, stream>>>(
        xb, wqkv, qkv, EMBED, QKVC, QKVC / 192);

    // 4. RMSNorm + RoPE on q,k inside packed qkv (8 rows/wave, table-driven)
    int rows = M_ROWS * NH + M_ROWS * NKV;   // 163840
    norm_rope<<<rows / 32, 256, 0, stream>>>(qkv, qnw, knw, rtab);

    // 5. attention -> abuf [4096][2048]
    attn_mfma<<<BB * NH * (SS / 64), 256, 0, stream>>>(qkv, am, sinks, abuf);

    // 6. output projection: fp32 into d_out, BM=256/BN=128, 16x16 = 256 blocks
    gemmW<float, 256, 128><<<256, 512, 0, stream>>>(
        abuf, wob, out, EMBED, EMBED, EMBED / 128);
}